// Round 10
// baseline (734.180 us; speedup 1.0000x reference)
//
#include <hip/hip_runtime.h>
#include <hip/hip_bf16.h>
#include <stdint.h>

// Swin windowed MHA: N=32, H=W=64, C=512, heads=16, head_dim=32, window 8x8 (E=64).
// conv x->bf16 ; transpose weights ; GEMM1 (128^2 tile, BK=32, 4 waves, 3-stage
// 2-deep prefetch, 3 blocks/CU, scatter epilogue to Q/K/VT) ; windowed attn ;
// GEMM2 (same structure, fp32 out).

typedef __attribute__((ext_vector_type(4))) float  f32x4;
typedef __attribute__((ext_vector_type(4))) float  fvec4;
typedef __attribute__((ext_vector_type(8))) short  s16x8;
typedef __attribute__((ext_vector_type(8))) __bf16 bf16x8;
typedef __attribute__((ext_vector_type(2))) unsigned int u32x2;
typedef unsigned short u16;
typedef unsigned int   u32;
typedef __attribute__((ext_vector_type(4))) u16 u16x4;
typedef __attribute__((ext_vector_type(8))) u16 u16x8;

__device__ __forceinline__ u16 f2bf(float f) {
  u32 u = __builtin_bit_cast(u32, f);
  u32 r = (u + 0x7FFFu + ((u >> 16) & 1u)) >> 16;
  return (u16)r;
}
__device__ __forceinline__ u32 pk2(float x, float y) {
  return (u32)f2bf(x) | ((u32)f2bf(y) << 16);
}

__device__ __forceinline__ f32x4 mfma16(s16x8 a, s16x8 b, f32x4 c) {
  return __builtin_amdgcn_mfma_f32_16x16x32_bf16((bf16x8)a, (bf16x8)b, c, 0, 0, 0);
}

__device__ __forceinline__ void gload16(const u16* g, u16* l) {
  __builtin_amdgcn_global_load_lds(
      (const __attribute__((address_space(1))) u32*)g,
      (__attribute__((address_space(3))) u32*)l, 16, 0, 0);
}

#define BARRIER() asm volatile("s_barrier" ::: "memory")
#define WAITVM(n) asm volatile("s_waitcnt vmcnt(" #n ")" ::: "memory")

// ---------------- conversion kernels ----------------
__global__ void k_conv_x(const float* __restrict__ x, u16* __restrict__ xb, int n8) {
  int i = blockIdx.x * 256 + threadIdx.x;
  if (i >= n8) return;
  fvec4 v0 = ((const fvec4*)x)[i * 2];
  fvec4 v1 = ((const fvec4*)x)[i * 2 + 1];
  u16x8 o;
  o[0] = f2bf(v0.x); o[1] = f2bf(v0.y); o[2] = f2bf(v0.z); o[3] = f2bf(v0.w);
  o[4] = f2bf(v1.x); o[5] = f2bf(v1.y); o[6] = f2bf(v1.z); o[7] = f2bf(v1.w);
  ((u16x8*)xb)[i] = o;
}

__global__ void k_transpose_w(const float* __restrict__ w, u16* __restrict__ wt, int K, int N) {
  int i = blockIdx.x * 256 + threadIdx.x;
  if (i >= K * N) return;
  int k = i / N, n = i - k * N;
  wt[n * K + k] = f2bf(w[i]);
}

// ---------------- GEMM: 128x128 tile, BK=32, 4 waves, 3-stage 2-deep prefetch ----------------
// A [M][512], B [N][512] bf16 row-major. MODE 0: qkv -> scatter Q/K/VT. MODE 1: fp32 Out.
// LDS 48 KiB: 3 stages x (A 8KB + B 8KB), reused as C-tile in the epilogue.
// Steady-state: STAGE(kt+2) issued, vmcnt(8) keeps 2 stages in flight (never 0 mid-loop).
template <int MODE>
__global__ __launch_bounds__(256, 3)
void k_gemm(const u16* __restrict__ A, const u16* __restrict__ B,
            const float* __restrict__ bias,
            u16* __restrict__ Qb, u16* __restrict__ Kb, u16* __restrict__ VT,
            float* __restrict__ Out, int ntn) {
  __shared__ u16 lds[24576];        // 48 KiB
  u16* ldsA = lds;                  // [3][4096]
  u16* ldsB = lds + 12288;          // [3][4096]
  const int tid = threadIdx.x;
  const int lane = tid & 63, wid = tid >> 6;
  const int quad = lane >> 4, col_l = lane & 15;
  const int wr = wid >> 1, wc = wid & 1;   // 2x2 waves, wave tile 64x64

  const int cpx = gridDim.x >> 3;
  const int sb = (blockIdx.x & 7) * cpx + (blockIdx.x >> 3);
  const int mt = sb / ntn, nt = sb - mt * ntn;
  const int m0 = mt * 128, n0 = nt * 128;

  // staging: chunk q in {tid, tid+256}; row=q>>2, pos=q&3; src chunk = pos^((row>>1)&3).
  const int sr = tid >> 2, sp_ = tid & 3;
  const size_t gA = (size_t)(m0 + sr) * 512 + (sp_ ^ ((sr >> 1) & 3)) * 8;
  const size_t gB = (size_t)(n0 + sr) * 512 + (sp_ ^ ((sr >> 1) & 3)) * 8;

  auto STAGE = [&](int s) {
    const int b = (s % 3) * 4096;
    const int k = s * 32;
    gload16(A + gA + k, &ldsA[b + tid * 8]);
    gload16(A + gA + 64 * 512 + k, &ldsA[b + 2048 + tid * 8]);
    gload16(B + gB + k, &ldsB[b + tid * 8]);
    gload16(B + gB + 64 * 512 + k, &ldsB[b + 2048 + tid * 8]);
  };

  STAGE(0);
  STAGE(1);
  f32x4 acc[4][4] = {};

  for (int kt = 0; kt < 16; ++kt) {
    const int bu = (kt % 3) * 4096;
    if (kt < 14)       { STAGE(kt + 2); WAITVM(8); }
    else if (kt == 14) { WAITVM(4); }
    else               { WAITVM(0); }
    BARRIER();
    s16x8 af[4], bf[4];
#pragma unroll
    for (int mf = 0; mf < 4; ++mf) {
      const int row = wr * 64 + mf * 16 + col_l;
      af[mf] = *(const s16x8*)&ldsA[bu + row * 32 + ((quad ^ ((row >> 1) & 3)) * 8)];
    }
#pragma unroll
    for (int nf = 0; nf < 4; ++nf) {
      const int row = wc * 64 + nf * 16 + col_l;
      bf[nf] = *(const s16x8*)&ldsB[bu + row * 32 + ((quad ^ ((row >> 1) & 3)) * 8)];
    }
    __builtin_amdgcn_s_setprio(1);
#pragma unroll
    for (int mf = 0; mf < 4; ++mf)
#pragma unroll
      for (int nf = 0; nf < 4; ++nf)
        acc[mf][nf] = mfma16(af[mf], bf[nf], acc[mf][nf]);
    __builtin_amdgcn_s_setprio(0);
    BARRIER();
  }

  // ---- epilogue via LDS (pipeline dead) ----
  const int hb0 = (m0 >> 6) & 63;     // even
  const int nimg = m0 >> 12;
  const int headbase = (n0 >> 5) & 15;

  if (MODE == 0) {
    const int which = n0 >> 9;        // 0=Q, 1=K, 2=V
    if (which < 2) {
      // [m][128] u16, chunk ^= m&7; 4x4 lane transpose -> 8B writes
      float bv[4];
#pragma unroll
      for (int c = 0; c < 4; ++c) bv[c] = bias[n0 + wc * 64 + c * 16 + col_l];
#pragma unroll
      for (int r = 0; r < 4; ++r) {
#pragma unroll
        for (int c = 0; c < 4; ++c) {
          float v0 = acc[r][c][0] + bv[c], v1 = acc[r][c][1] + bv[c];
          float v2 = acc[r][c][2] + bv[c], v3 = acc[r][c][3] + bv[c];
          float sA = (lane & 1) ? v0 : v1; sA = __shfl_xor(sA, 1);
          float sB = (lane & 1) ? v2 : v3; sB = __shfl_xor(sB, 1);
          u32 a, b;
          if (lane & 1) { a = pk2(sA, v1); b = pk2(sB, v3); }
          else          { a = pk2(v0, sA); b = pk2(v2, sB); }
          u32 s2 = (lane & 2) ? a : b;
          s2 = (u32)__shfl_xor((int)s2, 2);
          u32x2 val;
          if (lane & 2) { val.x = s2; val.y = b; }
          else          { val.x = a;  val.y = s2; }
          const int m = wr * 64 + r * 16 + quad * 4 + (col_l & 3);
          const int nc = wc * 64 + c * 16 + (col_l & ~3);
          *(u32x2*)&lds[m * 128 + (((nc >> 3) ^ (m & 7)) * 8) + ((nc >> 2) & 1) * 4] = val;
        }
      }
      __syncthreads();
      u16* dst = (which == 0) ? Qb : Kb;
#pragma unroll
      for (int it = 0; it < 8; ++it) {
        const int hh = (tid >> 7) & 1, wl = (tid >> 4) & 7;
        const int head_l = (tid >> 2) & 3, dch = tid & 3;
        const int m_loc = hh * 64 + it * 8 + wl;
        s16x8 val = *(const s16x8*)&lds[m_loc * 128 + (((head_l * 4 + dch) ^ (m_loc & 7)) * 8)];
        const int win = nimg * 64 + (hb0 >> 3) * 8 + it;
        const int e = ((hb0 & 7) + hh) * 8 + wl;
        const int head = headbase + head_l;
        *(s16x8*)&dst[(((size_t)win * 16 + head) * 64 + e) * 32 + dch * 8] = val;
      }
    } else {
      // V: [n][128] u16 (transposed), direct 8B writes, chunk ^= n&7
#pragma unroll
      for (int c = 0; c < 4; ++c) {
        const float bv = bias[n0 + wc * 64 + c * 16 + col_l];
        const int n = wc * 64 + c * 16 + col_l;
#pragma unroll
        for (int r = 0; r < 4; ++r) {
          const int mloc = wr * 64 + r * 16 + quad * 4;
          u32x2 val;
          val.x = pk2(acc[r][c][0] + bv, acc[r][c][1] + bv);
          val.y = pk2(acc[r][c][2] + bv, acc[r][c][3] + bv);
          *(u32x2*)&lds[n * 128 + (((mloc >> 3) ^ (n & 7)) * 8) + ((mloc >> 2) & 1) * 4] = val;
        }
      }
      __syncthreads();
#pragma unroll
      for (int it = 0; it < 8; ++it) {
        const int head_l = it & 3, dhi = it >> 2;
        const int wb = tid & 7, hh = (tid >> 3) & 1, dlow = (tid >> 4) & 15;
        const int d = dhi * 16 + dlow;
        const int n_loc = head_l * 32 + d;
        const int chunk = hh * 8 + wb;
        s16x8 val = *(const s16x8*)&lds[n_loc * 128 + ((chunk ^ (n_loc & 7)) * 8)];
        const int win = nimg * 64 + (hb0 >> 3) * 8 + wb;
        const int head = headbase + head_l;
        const int e0 = ((hb0 & 7) + hh) * 8;
        *(s16x8*)&VT[(((size_t)win * 16 + head) * 32 + d) * 64 + e0] = val;
      }
    }
  } else {
    // MODE 1: fp32 out, two 64-row passes through LDS (f32 [64][128] = 32 KB)
#pragma unroll
    for (int p = 0; p < 2; ++p) {
      if (p) __syncthreads();
      if (wr == p) {
#pragma unroll
        for (int c = 0; c < 4; ++c) {
          const float bv = bias[n0 + wc * 64 + c * 16 + col_l];
#pragma unroll
          for (int r = 0; r < 4; ++r) {
            float v0 = acc[r][c][0] + bv, v1 = acc[r][c][1] + bv;
            float v2 = acc[r][c][2] + bv, v3 = acc[r][c][3] + bv;
            float sA = (lane & 1) ? v0 : v1; sA = __shfl_xor(sA, 1);
            float sB = (lane & 1) ? v2 : v3; sB = __shfl_xor(sB, 1);
            float A0, A1, B0, B1;
            if (lane & 1) { A0 = sA; A1 = v1; B0 = sB; B1 = v3; }
            else          { A0 = v0; A1 = sA; B0 = v2; B1 = sB; }
            float t0 = (lane & 2) ? A0 : B0; t0 = __shfl_xor(t0, 2);
            float t1 = (lane & 2) ? A1 : B1; t1 = __shfl_xor(t1, 2);
            f32x4 outv;
            if (lane & 2) { outv[0] = t0; outv[1] = t1; outv[2] = B0; outv[3] = B1; }
            else          { outv[0] = A0; outv[1] = A1; outv[2] = t0; outv[3] = t1; }
            const int lr = r * 16 + quad * 4 + (col_l & 3);
            const int ck = (wc * 64 + c * 16 + (col_l & ~3)) >> 2;
            *(f32x4*)((char*)lds + lr * 512 + ((ck ^ (lr & 7)) << 4)) = outv;
          }
        }
      }
      __syncthreads();
#pragma unroll
      for (int it = 0; it < 8; ++it) {
        const int row = it * 8 + (tid >> 5);
        const int cl = tid & 31;
        f32x4 v = *(const f32x4*)((char*)lds + row * 512 + ((cl ^ (row & 7)) << 4));
        const int m = m0 + p * 64 + row;
        *(f32x4*)&Out[(size_t)m * 512 + n0 + cl * 4] = v;
      }
    }
  }
}

// ---------------- windowed attention (r3, unchanged) ----------------
__global__ __launch_bounds__(256, 2)
void k_attn(const u16* __restrict__ Q, const u16* __restrict__ K,
            const u16* __restrict__ VT, const float* __restrict__ mask,
            const float* __restrict__ btab, u16* __restrict__ AO) {
  __shared__ u16 plds[4 * 4096];
  const int tid = threadIdx.x;
  const int wid = tid >> 6, lane = tid & 63;
  const int quad = lane >> 4, col_l = lane & 15;
  const int bid = blockIdx.x;
  const int win = bid >> 2;
  const int head = ((bid & 3) << 2) | wid;
  const int nimg = win >> 6, a = (win >> 3) & 7, b = win & 7;
  const size_t wh = (size_t)(win * 16 + head);
  const u16* qb  = Q  + wh * 2048;
  const u16* kb  = K  + wh * 2048;
  const u16* vtb = VT + wh * 2048;

  s16x8 aq[4], bk[4];
#pragma unroll
  for (int t = 0; t < 4; ++t) {
    aq[t] = *(const s16x8*)&qb[(t * 16 + col_l) * 32 + quad * 8];
    bk[t] = *(const s16x8*)&kb[(t * 16 + col_l) * 32 + quad * 8];
  }
  f32x4 s[4][4] = {};
#pragma unroll
  for (int r = 0; r < 4; ++r)
#pragma unroll
    for (int c = 0; c < 4; ++c)
      s[r][c] = mfma16(aq[r], bk[c], s[r][c]);

  const float scale = 0.17677669529663687f;  // 1/sqrt(32)
  const float* mrow = mask + (size_t)(a * 8 + b) * 4096;
#pragma unroll
  for (int r = 0; r < 4; ++r)
#pragma unroll
    for (int c = 0; c < 4; ++c)
#pragma unroll
      for (int i = 0; i < 4; ++i) {
        const int row = r * 16 + quad * 4 + i, col = c * 16 + col_l;
        const int dh = (row >> 3) - (col >> 3) + 7;
        const int dw = (row & 7) - (col & 7) + 7;
        s[r][c][i] = s[r][c][i] * scale + btab[(dh * 15 + dw) * 16 + head] +
                     mrow[row * 64 + col];
      }

  float rinv[4][4];
#pragma unroll
  for (int r = 0; r < 4; ++r) {
#pragma unroll
    for (int i = 0; i < 4; ++i) {
      float mx = fmaxf(fmaxf(s[r][0][i], s[r][1][i]), fmaxf(s[r][2][i], s[r][3][i]));
      mx = fmaxf(mx, __shfl_xor(mx, 1));
      mx = fmaxf(mx, __shfl_xor(mx, 2));
      mx = fmaxf(mx, __shfl_xor(mx, 4));
      mx = fmaxf(mx, __shfl_xor(mx, 8));
      float sum = 0.f;
#pragma unroll
      for (int c = 0; c < 4; ++c) {
        float p = __expf(s[r][c][i] - mx);
        s[r][c][i] = p;
        sum += p;
      }
      sum += __shfl_xor(sum, 1);
      sum += __shfl_xor(sum, 2);
      sum += __shfl_xor(sum, 4);
      sum += __shfl_xor(sum, 8);
      rinv[r][i] = 1.0f / sum;
    }
  }

  u16* pl = &plds[wid * 4096];
#pragma unroll
  for (int r = 0; r < 4; ++r)
#pragma unroll
    for (int c = 0; c < 4; ++c)
#pragma unroll
      for (int i = 0; i < 4; ++i) {
        const int row = r * 16 + quad * 4 + i, col = c * 16 + col_l;
        const int off = (row * 128 + col * 2) ^ ((row & 7) << 4);
        *(u16*)((char*)pl + off) = f2bf(s[r][c][i]);
      }
  __syncthreads();

  s16x8 bv[2][2];
#pragma unroll
  for (int c2 = 0; c2 < 2; ++c2)
#pragma unroll
    for (int ks = 0; ks < 2; ++ks)
      bv[c2][ks] = *(const s16x8*)&vtb[(c2 * 16 + col_l) * 64 + ks * 32 + quad * 8];

  f32x4 o[4][2] = {};
#pragma unroll
  for (int r = 0; r < 4; ++r) {
#pragma unroll
    for (int ks = 0; ks < 2; ++ks) {
      const int row = r * 16 + col_l;
      const int off = (row * 128 + (ks * 32 + quad * 8) * 2) ^ ((row & 7) << 4);
      s16x8 pa = *(const s16x8*)((char*)pl + off);
#pragma unroll
      for (int c2 = 0; c2 < 2; ++c2)
        o[r][c2] = mfma16(pa, bv[c2][ks], o[r][c2]);
    }
  }

#pragma unroll
  for (int r = 0; r < 4; ++r) {
#pragma unroll
    for (int i = 0; i < 4; ++i) {
      const int row = r * 16 + quad * 4 + i;
      const int h = a * 8 + (row >> 3), w = b * 8 + (row & 7);
      const size_t m = (size_t)nimg * 4096 + (size_t)h * 64 + w;
      const float inv = rinv[r][i];
#pragma unroll
      for (int c2 = 0; c2 < 2; ++c2)
        AO[m * 512 + head * 32 + c2 * 16 + col_l] = f2bf(o[r][c2][i] * inv);
    }
  }
}

// ---------------- launch ----------------
extern "C" void kernel_launch(void* const* d_in, const int* in_sizes, int n_in,
                              void* d_out, int out_size, void* d_ws, size_t ws_size,
                              hipStream_t stream) {
  const float* x     = (const float*)d_in[0];
  const float* mask  = (const float*)d_in[1];
  const float* qkv_w = (const float*)d_in[2];
  const float* qkv_b = (const float*)d_in[3];
  const float* out_w = (const float*)d_in[4];
  const float* out_b = (const float*)d_in[5];
  const float* btab  = (const float*)d_in[6];

  char* ws = (char*)d_ws;
  u16* xb    = (u16*)ws;                        // 134,217,728 B (x bf16, reused as attn_out)
  u16* vt    = (u16*)(ws + 134217728);          // 134,217,728 B (V^T)
  u16* wqkvT = (u16*)(ws + 268435456);          // 1,572,864 B
  u16* woT   = (u16*)(ws + 270008320);          // 524,288 B

  u16* Qb = (u16*)d_out;                        // 134,217,728 B
  u16* Kb = (u16*)d_out + 67108864;             // 134,217,728 B

  k_conv_x<<<32768, 256, 0, stream>>>(x, xb, 8388608);
  k_transpose_w<<<3072, 256, 0, stream>>>(qkv_w, wqkvT, 512, 1536);
  k_transpose_w<<<1024, 256, 0, stream>>>(out_w, woT, 512, 512);
  k_gemm<0><<<12288, 256, 0, stream>>>(xb, wqkvT, qkv_b, Qb, Kb, vt, nullptr, 12);
  k_attn<<<8192, 256, 0, stream>>>(Qb, Kb, vt, mask, btab, xb);
  k_gemm<1><<<4096, 256, 0, stream>>>(xb, woT, out_b, nullptr, nullptr, nullptr,
                                      (float*)d_out, 4);
}

// Round 11
// 724.298 us; speedup vs baseline: 1.0136x; 1.0136x over previous
//
#include <hip/hip_runtime.h>
#include <hip/hip_bf16.h>
#include <stdint.h>

// Swin windowed MHA: N=32, H=W=64, C=512, heads=16, head_dim=32, window 8x8 (E=64).
// transpose weights ; GEMM1 (128^2 tile, BK=32, 4 waves, 4 blocks/CU, A staged from
// f32 x with in-kernel bf16 convert [fused conv], scatter epilogue to Q/K/VT) ;
// windowed attn ; GEMM2 (r9 structure, fp32 out).

typedef __attribute__((ext_vector_type(4))) float  f32x4;
typedef __attribute__((ext_vector_type(4))) float  fvec4;
typedef __attribute__((ext_vector_type(8))) short  s16x8;
typedef __attribute__((ext_vector_type(8))) __bf16 bf16x8;
typedef __attribute__((ext_vector_type(2))) unsigned int u32x2;
typedef unsigned short u16;
typedef unsigned int   u32;
typedef __attribute__((ext_vector_type(4))) u16 u16x4;
typedef __attribute__((ext_vector_type(8))) u16 u16x8;

__device__ __forceinline__ u16 f2bf(float f) {
  u32 u = __builtin_bit_cast(u32, f);
  u32 r = (u + 0x7FFFu + ((u >> 16) & 1u)) >> 16;
  return (u16)r;
}
__device__ __forceinline__ u32 pk2(float x, float y) {
  return (u32)f2bf(x) | ((u32)f2bf(y) << 16);
}

__device__ __forceinline__ f32x4 mfma16(s16x8 a, s16x8 b, f32x4 c) {
  return __builtin_amdgcn_mfma_f32_16x16x32_bf16((bf16x8)a, (bf16x8)b, c, 0, 0, 0);
}

__device__ __forceinline__ void gload16(const u16* g, u16* l) {
  __builtin_amdgcn_global_load_lds(
      (const __attribute__((address_space(1))) u32*)g,
      (__attribute__((address_space(3))) u32*)l, 16, 0, 0);
}

#define BARRIER() asm volatile("s_barrier" ::: "memory")
#define WAITVM(n) asm volatile("s_waitcnt vmcnt(" #n ")" ::: "memory")
#define WAITLG0() asm volatile("s_waitcnt lgkmcnt(0)" ::: "memory")

// ---------------- weight transpose ----------------
__global__ void k_transpose_w(const float* __restrict__ w, u16* __restrict__ wt, int K, int N) {
  int i = blockIdx.x * 256 + threadIdx.x;
  if (i >= K * N) return;
  int k = i / N, n = i - k * N;
  wt[n * K + k] = f2bf(w[i]);
}

// ---------------- GEMM: 128x128 tile, BK=32, 4 waves, dbuf, 4 blocks/CU ----------------
// MODE 0: A = f32 x (converted in staging, 2-deep reg pipeline), scatter -> Q/K/VT.
// MODE 1: A = bf16 [M][512] via global_load_lds, fp32 Out.
// LDS 32 KiB: A dbuf 2x8KB + B dbuf 2x8KB, reused as C-tile in the epilogue.
// Chunk swizzle: 16B-chunk pos ^= (row>>1)&3.
template <int MODE>
__global__ __launch_bounds__(256, 4)
void k_gemm(const float* __restrict__ Xf, const u16* __restrict__ A,
            const u16* __restrict__ B, const float* __restrict__ bias,
            u16* __restrict__ Qb, u16* __restrict__ Kb, u16* __restrict__ VT,
            float* __restrict__ Out, int ntn) {
  __shared__ u16 lds[16384];        // 32 KiB
  u16* ldsA = lds;                  // [2][4096]
  u16* ldsB = lds + 8192;           // [2][4096]
  const int tid = threadIdx.x;
  const int lane = tid & 63, wid = tid >> 6;
  const int quad = lane >> 4, col_l = lane & 15;
  const int wr = wid >> 1, wc = wid & 1;   // 2x2 waves, wave tile 64x64

  const int cpx = gridDim.x >> 3;
  const int sb = (blockIdx.x & 7) * cpx + (blockIdx.x >> 3);
  const int mt = sb / ntn, nt = sb - mt * ntn;
  const int m0 = mt * 128, n0 = nt * 128;

  const int sr = tid >> 2, sp_ = tid & 3;
  const int sch = sp_ ^ ((sr >> 1) & 3);
  const size_t gB = (size_t)(n0 + sr) * 512 + sch * 8;

  // MODE 0 A-staging: f32 source, 2-deep register pipeline, cvt + ds_write_b128.
  fvec4 ra[4];
  const float* gXf = Xf + (size_t)(m0 + sr) * 512 + sch * 8;
  auto LOADA = [&](int s) {
    const float* src = gXf + s * 32;
    ra[0] = *(const fvec4*)src;
    ra[1] = *(const fvec4*)(src + 4);
    ra[2] = *(const fvec4*)(src + 64 * 512);
    ra[3] = *(const fvec4*)(src + 64 * 512 + 4);
  };
  auto CVTW = [&](int s) {
    const int b = (s & 1) * 4096;
    u16x8 o0, o1;
#pragma unroll
    for (int j = 0; j < 4; ++j) {
      o0[j] = f2bf(ra[0][j]); o0[4 + j] = f2bf(ra[1][j]);
      o1[j] = f2bf(ra[2][j]); o1[4 + j] = f2bf(ra[3][j]);
    }
    *(u16x8*)&ldsA[b + tid * 8] = o0;
    *(u16x8*)&ldsA[b + 2048 + tid * 8] = o1;
  };
  auto STAGEB = [&](int s) {
    const int b = (s & 1) * 4096;
    const int k = s * 32;
    gload16(B + gB + k, &ldsB[b + tid * 8]);
    gload16(B + gB + 64 * 512 + k, &ldsB[b + 2048 + tid * 8]);
  };
  // MODE 1 staging (r9): both A and B via global_load_lds.
  const size_t gA1 = (MODE == 1) ? ((size_t)(m0 + sr) * 512 + sch * 8) : 0;
  auto STAGE1 = [&](int s) {
    const int b = (s & 1) * 4096;
    const int k = s * 32;
    gload16(A + gA1 + k, &ldsA[b + tid * 8]);
    gload16(A + gA1 + 64 * 512 + k, &ldsA[b + 2048 + tid * 8]);
    gload16(B + gB + k, &ldsB[b + tid * 8]);
    gload16(B + gB + 64 * 512 + k, &ldsB[b + 2048 + tid * 8]);
  };

  if (MODE == 0) {
    LOADA(0); CVTW(0);        // stage 0 A written
    LOADA(1);                 // stage 1 A in regs
    STAGEB(0);                // B(0) in flight
  } else {
    STAGE1(0);
  }
  f32x4 acc[4][4] = {};

  for (int kt = 0; kt < 16; ++kt) {
    const int bu = (kt & 1) * 4096;
    if (MODE == 0) {
      if (kt < 15) CVTW(kt + 1);     // implicit vmcnt drains A(kt+1), leaves B(kt)
      if (kt < 14) LOADA(kt + 2);
      if (kt < 15) STAGEB(kt + 1);
      if (kt < 14)       { WAITVM(6); }   // drain B(kt); A(kt+2)+B(kt+1) in flight
      else if (kt == 14) { WAITVM(2); }
      else               { WAITVM(0); }
      WAITLG0();                     // publish ds_writes before barrier
    } else {
      if (kt < 15) { STAGE1(kt + 1); WAITVM(4); }
      else         { WAITVM(0); }
    }
    BARRIER();
    s16x8 af[4], bf[4];
#pragma unroll
    for (int mf = 0; mf < 4; ++mf) {
      const int row = wr * 64 + mf * 16 + col_l;
      af[mf] = *(const s16x8*)&ldsA[bu + row * 32 + ((quad ^ ((row >> 1) & 3)) * 8)];
    }
#pragma unroll
    for (int nf = 0; nf < 4; ++nf) {
      const int row = wc * 64 + nf * 16 + col_l;
      bf[nf] = *(const s16x8*)&ldsB[bu + row * 32 + ((quad ^ ((row >> 1) & 3)) * 8)];
    }
    __builtin_amdgcn_s_setprio(1);
#pragma unroll
    for (int mf = 0; mf < 4; ++mf)
#pragma unroll
      for (int nf = 0; nf < 4; ++nf)
        acc[mf][nf] = mfma16(af[mf], bf[nf], acc[mf][nf]);
    __builtin_amdgcn_s_setprio(0);
    BARRIER();
  }

  // ---- epilogue via LDS (dbuf dead) ----
  const int hb0 = (m0 >> 6) & 63;     // even
  const int nimg = m0 >> 12;
  const int headbase = (n0 >> 5) & 15;

  if (MODE == 0) {
    const int which = n0 >> 9;        // 0=Q, 1=K, 2=V
    if (which < 2) {
      float bv[4];
#pragma unroll
      for (int c = 0; c < 4; ++c) bv[c] = bias[n0 + wc * 64 + c * 16 + col_l];
#pragma unroll
      for (int r = 0; r < 4; ++r) {
#pragma unroll
        for (int c = 0; c < 4; ++c) {
          float v0 = acc[r][c][0] + bv[c], v1 = acc[r][c][1] + bv[c];
          float v2 = acc[r][c][2] + bv[c], v3 = acc[r][c][3] + bv[c];
          float sA = (lane & 1) ? v0 : v1; sA = __shfl_xor(sA, 1);
          float sB = (lane & 1) ? v2 : v3; sB = __shfl_xor(sB, 1);
          u32 a, b;
          if (lane & 1) { a = pk2(sA, v1); b = pk2(sB, v3); }
          else          { a = pk2(v0, sA); b = pk2(v2, sB); }
          u32 s2 = (lane & 2) ? a : b;
          s2 = (u32)__shfl_xor((int)s2, 2);
          u32x2 val;
          if (lane & 2) { val.x = s2; val.y = b; }
          else          { val.x = a;  val.y = s2; }
          const int m = wr * 64 + r * 16 + quad * 4 + (col_l & 3);
          const int nc = wc * 64 + c * 16 + (col_l & ~3);
          *(u32x2*)&lds[m * 128 + (((nc >> 3) ^ (m & 7)) * 8) + ((nc >> 2) & 1) * 4] = val;
        }
      }
      __syncthreads();
      u16* dst = (which == 0) ? Qb : Kb;
#pragma unroll
      for (int it = 0; it < 8; ++it) {
        const int hh = (tid >> 7) & 1, wl = (tid >> 4) & 7;
        const int head_l = (tid >> 2) & 3, dch = tid & 3;
        const int m_loc = hh * 64 + it * 8 + wl;
        s16x8 val = *(const s16x8*)&lds[m_loc * 128 + (((head_l * 4 + dch) ^ (m_loc & 7)) * 8)];
        const int win = nimg * 64 + (hb0 >> 3) * 8 + it;
        const int e = ((hb0 & 7) + hh) * 8 + wl;
        const int head = headbase + head_l;
        *(s16x8*)&dst[(((size_t)win * 16 + head) * 64 + e) * 32 + dch * 8] = val;
      }
    } else {
#pragma unroll
      for (int c = 0; c < 4; ++c) {
        const float bv = bias[n0 + wc * 64 + c * 16 + col_l];
        const int n = wc * 64 + c * 16 + col_l;
#pragma unroll
        for (int r = 0; r < 4; ++r) {
          const int mloc = wr * 64 + r * 16 + quad * 4;
          u32x2 val;
          val.x = pk2(acc[r][c][0] + bv, acc[r][c][1] + bv);
          val.y = pk2(acc[r][c][2] + bv, acc[r][c][3] + bv);
          *(u32x2*)&lds[n * 128 + (((mloc >> 3) ^ (n & 7)) * 8) + ((mloc >> 2) & 1) * 4] = val;
        }
      }
      __syncthreads();
#pragma unroll
      for (int it = 0; it < 8; ++it) {
        const int head_l = it & 3, dhi = it >> 2;
        const int wb = tid & 7, hh = (tid >> 3) & 1, dlow = (tid >> 4) & 15;
        const int d = dhi * 16 + dlow;
        const int n_loc = head_l * 32 + d;
        const int chunk = hh * 8 + wb;
        s16x8 val = *(const s16x8*)&lds[n_loc * 128 + ((chunk ^ (n_loc & 7)) * 8)];
        const int win = nimg * 64 + (hb0 >> 3) * 8 + wb;
        const int head = headbase + head_l;
        const int e0 = ((hb0 & 7) + hh) * 8;
        *(s16x8*)&VT[(((size_t)win * 16 + head) * 32 + d) * 64 + e0] = val;
      }
    }
  } else {
#pragma unroll
    for (int p = 0; p < 2; ++p) {
      if (p) __syncthreads();
      if (wr == p) {
#pragma unroll
        for (int c = 0; c < 4; ++c) {
          const float bv = bias[n0 + wc * 64 + c * 16 + col_l];
#pragma unroll
          for (int r = 0; r < 4; ++r) {
            float v0 = acc[r][c][0] + bv, v1 = acc[r][c][1] + bv;
            float v2 = acc[r][c][2] + bv, v3 = acc[r][c][3] + bv;
            float sA = (lane & 1) ? v0 : v1; sA = __shfl_xor(sA, 1);
            float sB = (lane & 1) ? v2 : v3; sB = __shfl_xor(sB, 1);
            float A0, A1, B0, B1;
            if (lane & 1) { A0 = sA; A1 = v1; B0 = sB; B1 = v3; }
            else          { A0 = v0; A1 = sA; B0 = v2; B1 = sB; }
            float t0 = (lane & 2) ? A0 : B0; t0 = __shfl_xor(t0, 2);
            float t1 = (lane & 2) ? A1 : B1; t1 = __shfl_xor(t1, 2);
            f32x4 outv;
            if (lane & 2) { outv[0] = t0; outv[1] = t1; outv[2] = B0; outv[3] = B1; }
            else          { outv[0] = A0; outv[1] = A1; outv[2] = t0; outv[3] = t1; }
            const int lr = r * 16 + quad * 4 + (col_l & 3);
            const int ck = (wc * 64 + c * 16 + (col_l & ~3)) >> 2;
            *(f32x4*)((char*)lds + lr * 512 + ((ck ^ (lr & 7)) << 4)) = outv;
          }
        }
      }
      __syncthreads();
#pragma unroll
      for (int it = 0; it < 8; ++it) {
        const int row = it * 8 + (tid >> 5);
        const int cl = tid & 31;
        f32x4 v = *(const f32x4*)((char*)lds + row * 512 + ((cl ^ (row & 7)) << 4));
        const int m = m0 + p * 64 + row;
        *(f32x4*)&Out[(size_t)m * 512 + n0 + cl * 4] = v;
      }
    }
  }
}

// ---------------- windowed attention (r3/r9, unchanged) ----------------
__global__ __launch_bounds__(256, 2)
void k_attn(const u16* __restrict__ Q, const u16* __restrict__ K,
            const u16* __restrict__ VT, const float* __restrict__ mask,
            const float* __restrict__ btab, u16* __restrict__ AO) {
  __shared__ u16 plds[4 * 4096];
  const int tid = threadIdx.x;
  const int wid = tid >> 6, lane = tid & 63;
  const int quad = lane >> 4, col_l = lane & 15;
  const int bid = blockIdx.x;
  const int win = bid >> 2;
  const int head = ((bid & 3) << 2) | wid;
  const int nimg = win >> 6, a = (win >> 3) & 7, b = win & 7;
  const size_t wh = (size_t)(win * 16 + head);
  const u16* qb  = Q  + wh * 2048;
  const u16* kb  = K  + wh * 2048;
  const u16* vtb = VT + wh * 2048;

  s16x8 aq[4], bk[4];
#pragma unroll
  for (int t = 0; t < 4; ++t) {
    aq[t] = *(const s16x8*)&qb[(t * 16 + col_l) * 32 + quad * 8];
    bk[t] = *(const s16x8*)&kb[(t * 16 + col_l) * 32 + quad * 8];
  }
  f32x4 s[4][4] = {};
#pragma unroll
  for (int r = 0; r < 4; ++r)
#pragma unroll
    for (int c = 0; c < 4; ++c)
      s[r][c] = mfma16(aq[r], bk[c], s[r][c]);

  const float scale = 0.17677669529663687f;  // 1/sqrt(32)
  const float* mrow = mask + (size_t)(a * 8 + b) * 4096;
#pragma unroll
  for (int r = 0; r < 4; ++r)
#pragma unroll
    for (int c = 0; c < 4; ++c)
#pragma unroll
      for (int i = 0; i < 4; ++i) {
        const int row = r * 16 + quad * 4 + i, col = c * 16 + col_l;
        const int dh = (row >> 3) - (col >> 3) + 7;
        const int dw = (row & 7) - (col & 7) + 7;
        s[r][c][i] = s[r][c][i] * scale + btab[(dh * 15 + dw) * 16 + head] +
                     mrow[row * 64 + col];
      }

  float rinv[4][4];
#pragma unroll
  for (int r = 0; r < 4; ++r) {
#pragma unroll
    for (int i = 0; i < 4; ++i) {
      float mx = fmaxf(fmaxf(s[r][0][i], s[r][1][i]), fmaxf(s[r][2][i], s[r][3][i]));
      mx = fmaxf(mx, __shfl_xor(mx, 1));
      mx = fmaxf(mx, __shfl_xor(mx, 2));
      mx = fmaxf(mx, __shfl_xor(mx, 4));
      mx = fmaxf(mx, __shfl_xor(mx, 8));
      float sum = 0.f;
#pragma unroll
      for (int c = 0; c < 4; ++c) {
        float p = __expf(s[r][c][i] - mx);
        s[r][c][i] = p;
        sum += p;
      }
      sum += __shfl_xor(sum, 1);
      sum += __shfl_xor(sum, 2);
      sum += __shfl_xor(sum, 4);
      sum += __shfl_xor(sum, 8);
      rinv[r][i] = 1.0f / sum;
    }
  }

  u16* pl = &plds[wid * 4096];
#pragma unroll
  for (int r = 0; r < 4; ++r)
#pragma unroll
    for (int c = 0; c < 4; ++c)
#pragma unroll
      for (int i = 0; i < 4; ++i) {
        const int row = r * 16 + quad * 4 + i, col = c * 16 + col_l;
        const int off = (row * 128 + col * 2) ^ ((row & 7) << 4);
        *(u16*)((char*)pl + off) = f2bf(s[r][c][i]);
      }
  __syncthreads();

  s16x8 bv[2][2];
#pragma unroll
  for (int c2 = 0; c2 < 2; ++c2)
#pragma unroll
    for (int ks = 0; ks < 2; ++ks)
      bv[c2][ks] = *(const s16x8*)&vtb[(c2 * 16 + col_l) * 64 + ks * 32 + quad * 8];

  f32x4 o[4][2] = {};
#pragma unroll
  for (int r = 0; r < 4; ++r) {
#pragma unroll
    for (int ks = 0; ks < 2; ++ks) {
      const int row = r * 16 + col_l;
      const int off = (row * 128 + (ks * 32 + quad * 8) * 2) ^ ((row & 7) << 4);
      s16x8 pa = *(const s16x8*)((char*)pl + off);
#pragma unroll
      for (int c2 = 0; c2 < 2; ++c2)
        o[r][c2] = mfma16(pa, bv[c2][ks], o[r][c2]);
    }
  }

#pragma unroll
  for (int r = 0; r < 4; ++r) {
#pragma unroll
    for (int i = 0; i < 4; ++i) {
      const int row = r * 16 + quad * 4 + i;
      const int h = a * 8 + (row >> 3), w = b * 8 + (row & 7);
      const size_t m = (size_t)nimg * 4096 + (size_t)h * 64 + w;
      const float inv = rinv[r][i];
#pragma unroll
      for (int c2 = 0; c2 < 2; ++c2)
        AO[m * 512 + head * 32 + c2 * 16 + col_l] = f2bf(o[r][c2][i] * inv);
    }
  }
}

// ---------------- launch ----------------
extern "C" void kernel_launch(void* const* d_in, const int* in_sizes, int n_in,
                              void* d_out, int out_size, void* d_ws, size_t ws_size,
                              hipStream_t stream) {
  const float* x     = (const float*)d_in[0];
  const float* mask  = (const float*)d_in[1];
  const float* qkv_w = (const float*)d_in[2];
  const float* qkv_b = (const float*)d_in[3];
  const float* out_w = (const float*)d_in[4];
  const float* out_b = (const float*)d_in[5];
  const float* btab  = (const float*)d_in[6];

  char* ws = (char*)d_ws;
  u16* ao    = (u16*)ws;                        // 134,217,728 B (attn out bf16)
  u16* vt    = (u16*)(ws + 134217728);          // 134,217,728 B (V^T)
  u16* wqkvT = (u16*)(ws + 268435456);          // 1,572,864 B
  u16* woT   = (u16*)(ws + 270008320);          // 524,288 B

  u16* Qb = (u16*)d_out;                        // 134,217,728 B
  u16* Kb = (u16*)d_out + 67108864;             // 134,217,728 B

  k_transpose_w<<<3072, 256, 0, stream>>>(qkv_w, wqkvT, 512, 1536);
  k_transpose_w<<<1024, 256, 0, stream>>>(out_w, woT, 512, 512);
  k_gemm<0><<<12288, 256, 0, stream>>>(x, nullptr, wqkvT, qkv_b, Qb, Kb, vt,
                                       nullptr, 12);
  k_attn<<<8192, 256, 0, stream>>>(Qb, Kb, vt, mask, btab, ao);
  k_gemm<1><<<4096, 256, 0, stream>>>(nullptr, ao, woT, out_b, nullptr, nullptr,
                                      nullptr, (float*)d_out, 4);
}

// Round 12
// 707.598 us; speedup vs baseline: 1.0376x; 1.0236x over previous
//
#include <hip/hip_runtime.h>
#include <hip/hip_bf16.h>
#include <stdint.h>

// Swin windowed MHA: N=32, H=W=64, C=512, heads=16, head_dim=32, window 8x8 (E=64).
// conv x->bf16 ; transpose weights ; GEMM1 (128^2 tile, BK=32, 4 waves, dbuf,
// 4 blocks/CU, scatter epilogue to Q/K/VT) ; windowed attn (4 blocks/CU) ;
// GEMM2 (same structure, fp32 out).  [r9 structure + attn occupancy]

typedef __attribute__((ext_vector_type(4))) float  f32x4;
typedef __attribute__((ext_vector_type(4))) float  fvec4;
typedef __attribute__((ext_vector_type(8))) short  s16x8;
typedef __attribute__((ext_vector_type(8))) __bf16 bf16x8;
typedef __attribute__((ext_vector_type(2))) unsigned int u32x2;
typedef unsigned short u16;
typedef unsigned int   u32;
typedef __attribute__((ext_vector_type(4))) u16 u16x4;
typedef __attribute__((ext_vector_type(8))) u16 u16x8;

__device__ __forceinline__ u16 f2bf(float f) {
  u32 u = __builtin_bit_cast(u32, f);
  u32 r = (u + 0x7FFFu + ((u >> 16) & 1u)) >> 16;
  return (u16)r;
}
__device__ __forceinline__ u32 pk2(float x, float y) {
  return (u32)f2bf(x) | ((u32)f2bf(y) << 16);
}

__device__ __forceinline__ f32x4 mfma16(s16x8 a, s16x8 b, f32x4 c) {
  return __builtin_amdgcn_mfma_f32_16x16x32_bf16((bf16x8)a, (bf16x8)b, c, 0, 0, 0);
}

__device__ __forceinline__ void gload16(const u16* g, u16* l) {
  __builtin_amdgcn_global_load_lds(
      (const __attribute__((address_space(1))) u32*)g,
      (__attribute__((address_space(3))) u32*)l, 16, 0, 0);
}

#define BARRIER() asm volatile("s_barrier" ::: "memory")
#define WAITVM(n) asm volatile("s_waitcnt vmcnt(" #n ")" ::: "memory")

// ---------------- conversion kernels ----------------
__global__ void k_conv_x(const float* __restrict__ x, u16* __restrict__ xb, int n8) {
  int i = blockIdx.x * 256 + threadIdx.x;
  if (i >= n8) return;
  fvec4 v0 = ((const fvec4*)x)[i * 2];
  fvec4 v1 = ((const fvec4*)x)[i * 2 + 1];
  u16x8 o;
  o[0] = f2bf(v0.x); o[1] = f2bf(v0.y); o[2] = f2bf(v0.z); o[3] = f2bf(v0.w);
  o[4] = f2bf(v1.x); o[5] = f2bf(v1.y); o[6] = f2bf(v1.z); o[7] = f2bf(v1.w);
  ((u16x8*)xb)[i] = o;
}

__global__ void k_transpose_w(const float* __restrict__ w, u16* __restrict__ wt, int K, int N) {
  int i = blockIdx.x * 256 + threadIdx.x;
  if (i >= K * N) return;
  int k = i / N, n = i - k * N;
  wt[n * K + k] = f2bf(w[i]);
}

// ---------------- GEMM: 128x128 tile, BK=32, 4 waves, dbuf, 4 blocks/CU (r9) ----------------
template <int MODE>
__global__ __launch_bounds__(256, 4)
void k_gemm(const u16* __restrict__ A, const u16* __restrict__ B,
            const float* __restrict__ bias,
            u16* __restrict__ Qb, u16* __restrict__ Kb, u16* __restrict__ VT,
            float* __restrict__ Out, int ntn) {
  __shared__ u16 lds[16384];        // 32 KiB
  u16* ldsA = lds;                  // [2][4096]
  u16* ldsB = lds + 8192;           // [2][4096]
  const int tid = threadIdx.x;
  const int lane = tid & 63, wid = tid >> 6;
  const int quad = lane >> 4, col_l = lane & 15;
  const int wr = wid >> 1, wc = wid & 1;   // 2x2 waves, wave tile 64x64

  const int cpx = gridDim.x >> 3;
  const int sb = (blockIdx.x & 7) * cpx + (blockIdx.x >> 3);
  const int mt = sb / ntn, nt = sb - mt * ntn;
  const int m0 = mt * 128, n0 = nt * 128;

  const int sr = tid >> 2, sp_ = tid & 3;
  const size_t gA = (size_t)(m0 + sr) * 512 + (sp_ ^ ((sr >> 1) & 3)) * 8;
  const size_t gB = (size_t)(n0 + sr) * 512 + (sp_ ^ ((sr >> 1) & 3)) * 8;

  auto STAGE = [&](int s) {
    const int b = (s & 1) * 4096;
    const int k = s * 32;
    gload16(A + gA + k, &ldsA[b + tid * 8]);
    gload16(A + gA + 64 * 512 + k, &ldsA[b + 2048 + tid * 8]);
    gload16(B + gB + k, &ldsB[b + tid * 8]);
    gload16(B + gB + 64 * 512 + k, &ldsB[b + 2048 + tid * 8]);
  };

  STAGE(0);
  f32x4 acc[4][4] = {};

  for (int kt = 0; kt < 16; ++kt) {
    const int bu = (kt & 1) * 4096;
    if (kt < 15) { STAGE(kt + 1); WAITVM(4); }
    else         { WAITVM(0); }
    BARRIER();
    s16x8 af[4], bf[4];
#pragma unroll
    for (int mf = 0; mf < 4; ++mf) {
      const int row = wr * 64 + mf * 16 + col_l;
      af[mf] = *(const s16x8*)&ldsA[bu + row * 32 + ((quad ^ ((row >> 1) & 3)) * 8)];
    }
#pragma unroll
    for (int nf = 0; nf < 4; ++nf) {
      const int row = wc * 64 + nf * 16 + col_l;
      bf[nf] = *(const s16x8*)&ldsB[bu + row * 32 + ((quad ^ ((row >> 1) & 3)) * 8)];
    }
    __builtin_amdgcn_s_setprio(1);
#pragma unroll
    for (int mf = 0; mf < 4; ++mf)
#pragma unroll
      for (int nf = 0; nf < 4; ++nf)
        acc[mf][nf] = mfma16(af[mf], bf[nf], acc[mf][nf]);
    __builtin_amdgcn_s_setprio(0);
    BARRIER();
  }

  // ---- epilogue via LDS (dbuf dead) ----
  const int hb0 = (m0 >> 6) & 63;     // even
  const int nimg = m0 >> 12;
  const int headbase = (n0 >> 5) & 15;

  if (MODE == 0) {
    const int which = n0 >> 9;        // 0=Q, 1=K, 2=V
    if (which < 2) {
      float bv[4];
#pragma unroll
      for (int c = 0; c < 4; ++c) bv[c] = bias[n0 + wc * 64 + c * 16 + col_l];
#pragma unroll
      for (int r = 0; r < 4; ++r) {
#pragma unroll
        for (int c = 0; c < 4; ++c) {
          float v0 = acc[r][c][0] + bv[c], v1 = acc[r][c][1] + bv[c];
          float v2 = acc[r][c][2] + bv[c], v3 = acc[r][c][3] + bv[c];
          float sA = (lane & 1) ? v0 : v1; sA = __shfl_xor(sA, 1);
          float sB = (lane & 1) ? v2 : v3; sB = __shfl_xor(sB, 1);
          u32 a, b;
          if (lane & 1) { a = pk2(sA, v1); b = pk2(sB, v3); }
          else          { a = pk2(v0, sA); b = pk2(v2, sB); }
          u32 s2 = (lane & 2) ? a : b;
          s2 = (u32)__shfl_xor((int)s2, 2);
          u32x2 val;
          if (lane & 2) { val.x = s2; val.y = b; }
          else          { val.x = a;  val.y = s2; }
          const int m = wr * 64 + r * 16 + quad * 4 + (col_l & 3);
          const int nc = wc * 64 + c * 16 + (col_l & ~3);
          *(u32x2*)&lds[m * 128 + (((nc >> 3) ^ (m & 7)) * 8) + ((nc >> 2) & 1) * 4] = val;
        }
      }
      __syncthreads();
      u16* dst = (which == 0) ? Qb : Kb;
#pragma unroll
      for (int it = 0; it < 8; ++it) {
        const int hh = (tid >> 7) & 1, wl = (tid >> 4) & 7;
        const int head_l = (tid >> 2) & 3, dch = tid & 3;
        const int m_loc = hh * 64 + it * 8 + wl;
        s16x8 val = *(const s16x8*)&lds[m_loc * 128 + (((head_l * 4 + dch) ^ (m_loc & 7)) * 8)];
        const int win = nimg * 64 + (hb0 >> 3) * 8 + it;
        const int e = ((hb0 & 7) + hh) * 8 + wl;
        const int head = headbase + head_l;
        *(s16x8*)&dst[(((size_t)win * 16 + head) * 64 + e) * 32 + dch * 8] = val;
      }
    } else {
#pragma unroll
      for (int c = 0; c < 4; ++c) {
        const float bv = bias[n0 + wc * 64 + c * 16 + col_l];
        const int n = wc * 64 + c * 16 + col_l;
#pragma unroll
        for (int r = 0; r < 4; ++r) {
          const int mloc = wr * 64 + r * 16 + quad * 4;
          u32x2 val;
          val.x = pk2(acc[r][c][0] + bv, acc[r][c][1] + bv);
          val.y = pk2(acc[r][c][2] + bv, acc[r][c][3] + bv);
          *(u32x2*)&lds[n * 128 + (((mloc >> 3) ^ (n & 7)) * 8) + ((mloc >> 2) & 1) * 4] = val;
        }
      }
      __syncthreads();
#pragma unroll
      for (int it = 0; it < 8; ++it) {
        const int head_l = it & 3, dhi = it >> 2;
        const int wb = tid & 7, hh = (tid >> 3) & 1, dlow = (tid >> 4) & 15;
        const int d = dhi * 16 + dlow;
        const int n_loc = head_l * 32 + d;
        const int chunk = hh * 8 + wb;
        s16x8 val = *(const s16x8*)&lds[n_loc * 128 + ((chunk ^ (n_loc & 7)) * 8)];
        const int win = nimg * 64 + (hb0 >> 3) * 8 + wb;
        const int head = headbase + head_l;
        const int e0 = ((hb0 & 7) + hh) * 8;
        *(s16x8*)&VT[(((size_t)win * 16 + head) * 32 + d) * 64 + e0] = val;
      }
    }
  } else {
#pragma unroll
    for (int p = 0; p < 2; ++p) {
      if (p) __syncthreads();
      if (wr == p) {
#pragma unroll
        for (int c = 0; c < 4; ++c) {
          const float bv = bias[n0 + wc * 64 + c * 16 + col_l];
#pragma unroll
          for (int r = 0; r < 4; ++r) {
            float v0 = acc[r][c][0] + bv, v1 = acc[r][c][1] + bv;
            float v2 = acc[r][c][2] + bv, v3 = acc[r][c][3] + bv;
            float sA = (lane & 1) ? v0 : v1; sA = __shfl_xor(sA, 1);
            float sB = (lane & 1) ? v2 : v3; sB = __shfl_xor(sB, 1);
            float A0, A1, B0, B1;
            if (lane & 1) { A0 = sA; A1 = v1; B0 = sB; B1 = v3; }
            else          { A0 = v0; A1 = sA; B0 = v2; B1 = sB; }
            float t0 = (lane & 2) ? A0 : B0; t0 = __shfl_xor(t0, 2);
            float t1 = (lane & 2) ? A1 : B1; t1 = __shfl_xor(t1, 2);
            f32x4 outv;
            if (lane & 2) { outv[0] = t0; outv[1] = t1; outv[2] = B0; outv[3] = B1; }
            else          { outv[0] = A0; outv[1] = A1; outv[2] = t0; outv[3] = t1; }
            const int lr = r * 16 + quad * 4 + (col_l & 3);
            const int ck = (wc * 64 + c * 16 + (col_l & ~3)) >> 2;
            *(f32x4*)((char*)lds + lr * 512 + ((ck ^ (lr & 7)) << 4)) = outv;
          }
        }
      }
      __syncthreads();
#pragma unroll
      for (int it = 0; it < 8; ++it) {
        const int row = it * 8 + (tid >> 5);
        const int cl = tid & 31;
        f32x4 v = *(const f32x4*)((char*)lds + row * 512 + ((cl ^ (row & 7)) << 4));
        const int m = m0 + p * 64 + row;
        *(f32x4*)&Out[(size_t)m * 512 + n0 + cl * 4] = v;
      }
    }
  }
}

// ---------------- windowed attention (r9 math, 4 blocks/CU) ----------------
__global__ __launch_bounds__(256, 4)
void k_attn(const u16* __restrict__ Q, const u16* __restrict__ K,
            const u16* __restrict__ VT, const float* __restrict__ mask,
            const float* __restrict__ btab, u16* __restrict__ AO) {
  __shared__ u16 plds[4 * 4096];
  const int tid = threadIdx.x;
  const int wid = tid >> 6, lane = tid & 63;
  const int quad = lane >> 4, col_l = lane & 15;
  const int bid = blockIdx.x;
  const int win = bid >> 2;
  const int head = ((bid & 3) << 2) | wid;
  const int nimg = win >> 6, a = (win >> 3) & 7, b = win & 7;
  const size_t wh = (size_t)(win * 16 + head);
  const u16* qb  = Q  + wh * 2048;
  const u16* kb  = K  + wh * 2048;
  const u16* vtb = VT + wh * 2048;

  s16x8 aq[4], bk[4];
#pragma unroll
  for (int t = 0; t < 4; ++t) {
    aq[t] = *(const s16x8*)&qb[(t * 16 + col_l) * 32 + quad * 8];
    bk[t] = *(const s16x8*)&kb[(t * 16 + col_l) * 32 + quad * 8];
  }
  f32x4 s[4][4] = {};
#pragma unroll
  for (int r = 0; r < 4; ++r)
#pragma unroll
    for (int c = 0; c < 4; ++c)
      s[r][c] = mfma16(aq[r], bk[c], s[r][c]);

  const float scale = 0.17677669529663687f;  // 1/sqrt(32)
  const float* mrow = mask + (size_t)(a * 8 + b) * 4096;
#pragma unroll
  for (int r = 0; r < 4; ++r)
#pragma unroll
    for (int c = 0; c < 4; ++c)
#pragma unroll
      for (int i = 0; i < 4; ++i) {
        const int row = r * 16 + quad * 4 + i, col = c * 16 + col_l;
        const int dh = (row >> 3) - (col >> 3) + 7;
        const int dw = (row & 7) - (col & 7) + 7;
        s[r][c][i] = s[r][c][i] * scale + btab[(dh * 15 + dw) * 16 + head] +
                     mrow[row * 64 + col];
      }

  float rinv[4][4];
#pragma unroll
  for (int r = 0; r < 4; ++r) {
#pragma unroll
    for (int i = 0; i < 4; ++i) {
      float mx = fmaxf(fmaxf(s[r][0][i], s[r][1][i]), fmaxf(s[r][2][i], s[r][3][i]));
      mx = fmaxf(mx, __shfl_xor(mx, 1));
      mx = fmaxf(mx, __shfl_xor(mx, 2));
      mx = fmaxf(mx, __shfl_xor(mx, 4));
      mx = fmaxf(mx, __shfl_xor(mx, 8));
      float sum = 0.f;
#pragma unroll
      for (int c = 0; c < 4; ++c) {
        float p = __expf(s[r][c][i] - mx);
        s[r][c][i] = p;
        sum += p;
      }
      sum += __shfl_xor(sum, 1);
      sum += __shfl_xor(sum, 2);
      sum += __shfl_xor(sum, 4);
      sum += __shfl_xor(sum, 8);
      rinv[r][i] = 1.0f / sum;
    }
  }

  u16* pl = &plds[wid * 4096];
#pragma unroll
  for (int r = 0; r < 4; ++r)
#pragma unroll
    for (int c = 0; c < 4; ++c)
#pragma unroll
      for (int i = 0; i < 4; ++i) {
        const int row = r * 16 + quad * 4 + i, col = c * 16 + col_l;
        const int off = (row * 128 + col * 2) ^ ((row & 7) << 4);
        *(u16*)((char*)pl + off) = f2bf(s[r][c][i]);
      }
  __syncthreads();

  s16x8 bv[2][2];
#pragma unroll
  for (int c2 = 0; c2 < 2; ++c2)
#pragma unroll
    for (int ks = 0; ks < 2; ++ks)
      bv[c2][ks] = *(const s16x8*)&vtb[(c2 * 16 + col_l) * 64 + ks * 32 + quad * 8];

  f32x4 o[4][2] = {};
#pragma unroll
  for (int r = 0; r < 4; ++r) {
#pragma unroll
    for (int ks = 0; ks < 2; ++ks) {
      const int row = r * 16 + col_l;
      const int off = (row * 128 + (ks * 32 + quad * 8) * 2) ^ ((row & 7) << 4);
      s16x8 pa = *(const s16x8*)((char*)pl + off);
#pragma unroll
      for (int c2 = 0; c2 < 2; ++c2)
        o[r][c2] = mfma16(pa, bv[c2][ks], o[r][c2]);
    }
  }

#pragma unroll
  for (int r = 0; r < 4; ++r) {
#pragma unroll
    for (int i = 0; i < 4; ++i) {
      const int row = r * 16 + quad * 4 + i;
      const int h = a * 8 + (row >> 3), w = b * 8 + (row & 7);
      const size_t m = (size_t)nimg * 4096 + (size_t)h * 64 + w;
      const float inv = rinv[r][i];
#pragma unroll
      for (int c2 = 0; c2 < 2; ++c2)
        AO[m * 512 + head * 32 + c2 * 16 + col_l] = f2bf(o[r][c2][i] * inv);
    }
  }
}

// ---------------- launch ----------------
extern "C" void kernel_launch(void* const* d_in, const int* in_sizes, int n_in,
                              void* d_out, int out_size, void* d_ws, size_t ws_size,
                              hipStream_t stream) {
  const float* x     = (const float*)d_in[0];
  const float* mask  = (const float*)d_in[1];
  const float* qkv_w = (const float*)d_in[2];
  const float* qkv_b = (const float*)d_in[3];
  const float* out_w = (const float*)d_in[4];
  const float* out_b = (const float*)d_in[5];
  const float* btab  = (const float*)d_in[6];

  char* ws = (char*)d_ws;
  u16* xb    = (u16*)ws;                        // 134,217,728 B (x bf16, reused as attn_out)
  u16* vt    = (u16*)(ws + 134217728);          // 134,217,728 B (V^T)
  u16* wqkvT = (u16*)(ws + 268435456);          // 1,572,864 B
  u16* woT   = (u16*)(ws + 270008320);          // 524,288 B

  u16* Qb = (u16*)d_out;                        // 134,217,728 B
  u16* Kb = (u16*)d_out + 67108864;             // 134,217,728 B

  k_conv_x<<<32768, 256, 0, stream>>>(x, xb, 8388608);
  k_transpose_w<<<3072, 256, 0, stream>>>(qkv_w, wqkvT, 512, 1536);
  k_transpose_w<<<1024, 256, 0, stream>>>(out_w, woT, 512, 512);
  k_gemm<0><<<12288, 256, 0, stream>>>(xb, wqkvT, qkv_b, Qb, Kb, vt, nullptr, 12);
  k_attn<<<8192, 256, 0, stream>>>(Qb, Kb, vt, mask, btab, xb);
  k_gemm<1><<<4096, 256, 0, stream>>>(xb, woT, out_b, nullptr, nullptr, nullptr,
                                      (float*)d_out, 4);
}

// Round 13
// 689.888 us; speedup vs baseline: 1.0642x; 1.0257x over previous
//
#include <hip/hip_runtime.h>
#include <hip/hip_bf16.h>
#include <stdint.h>

// Swin windowed MHA: N=32, H=W=64, C=512, heads=16, head_dim=32, window 8x8 (E=64).
// conv x->bf16 ; transpose weights ; k_winfuse (fused QKV-proj GEMM + windowed attn:
// block = (window, head-quad), 4 waves, LDS-staged B, 2 blocks/CU, 256-VGPR budget) ;
// GEMM2 (r9/r12 structure, fp32 out).

typedef __attribute__((ext_vector_type(4))) float  f32x4;
typedef __attribute__((ext_vector_type(4))) float  fvec4;
typedef __attribute__((ext_vector_type(8))) short  s16x8;
typedef __attribute__((ext_vector_type(8))) __bf16 bf16x8;
typedef __attribute__((ext_vector_type(2))) unsigned int u32x2;
typedef __attribute__((ext_vector_type(4))) unsigned int u32x4;
typedef unsigned short u16;
typedef unsigned int   u32;
typedef __attribute__((ext_vector_type(4))) u16 u16x4;
typedef __attribute__((ext_vector_type(8))) u16 u16x8;

__device__ __forceinline__ u16 f2bf(float f) {
  u32 u = __builtin_bit_cast(u32, f);
  u32 r = (u + 0x7FFFu + ((u >> 16) & 1u)) >> 16;
  return (u16)r;
}
__device__ __forceinline__ u32 pk2(float x, float y) {
  return (u32)f2bf(x) | ((u32)f2bf(y) << 16);
}

__device__ __forceinline__ f32x4 mfma16(s16x8 a, s16x8 b, f32x4 c) {
  return __builtin_amdgcn_mfma_f32_16x16x32_bf16((bf16x8)a, (bf16x8)b, c, 0, 0, 0);
}

__device__ __forceinline__ void gload16(const u16* g, u16* l) {
  __builtin_amdgcn_global_load_lds(
      (const __attribute__((address_space(1))) u32*)g,
      (__attribute__((address_space(3))) u32*)l, 16, 0, 0);
}

#define BARRIER() asm volatile("s_barrier" ::: "memory")
#define WAITVM(n) asm volatile("s_waitcnt vmcnt(" #n ")" ::: "memory")

// ---------------- conversion kernels ----------------
__global__ void k_conv_x(const float* __restrict__ x, u16* __restrict__ xb, int n8) {
  int i = blockIdx.x * 256 + threadIdx.x;
  if (i >= n8) return;
  fvec4 v0 = ((const fvec4*)x)[i * 2];
  fvec4 v1 = ((const fvec4*)x)[i * 2 + 1];
  u16x8 o;
  o[0] = f2bf(v0.x); o[1] = f2bf(v0.y); o[2] = f2bf(v0.z); o[3] = f2bf(v0.w);
  o[4] = f2bf(v1.x); o[5] = f2bf(v1.y); o[6] = f2bf(v1.z); o[7] = f2bf(v1.w);
  ((u16x8*)xb)[i] = o;
}

__global__ void k_transpose_w(const float* __restrict__ w, u16* __restrict__ wt, int K, int N) {
  int i = blockIdx.x * 256 + threadIdx.x;
  if (i >= K * N) return;
  int k = i / N, n = i - k * N;
  wt[n * K + k] = f2bf(w[i]);
}

// ---------------- fused QKV-proj + windowed attention ----------------
// Block = (window, head-quad): 8192 blocks, 256 thr = 4 waves, wave wid owns head hq*4+wid.
// Proj: M=64 (window rows), N=384 (4 heads x [Q32|K32|V32]), K=512, BK=32, r9 dbuf loop.
// LDS 56KB: A dbuf [2][2048]u16 @0, B dbuf [2][12288]u16 @4096; attn scratch (4KB Q+K /
// 8KB P per wave) overlays the dead B region after the K-loop. 2 blocks/CU -> 256 VGPR.
__global__ __launch_bounds__(256, 2)
void k_winfuse(const u16* __restrict__ xb, const u16* __restrict__ wqkvT,
               const float* __restrict__ qkv_b, const float* __restrict__ mask,
               const float* __restrict__ btab, u16* __restrict__ AO) {
  __shared__ u16 lds[28672];   // 56 KiB
  u16* ldsA = lds;             // [2][2048]
  u16* ldsB = lds + 4096;      // [2][12288]
  const int tid = threadIdx.x;
  const int lane = tid & 63, wid = tid >> 6;
  const int quad = lane >> 4, col_l = lane & 15;

  // same-window blocks contiguous on one XCD
  const int sb = (blockIdx.x & 7) * 1024 + (blockIdx.x >> 3);
  const int win = sb >> 2, hq = sb & 3;
  const int nimg = win >> 6, a = (win >> 3) & 7, b = win & 7;
  const int head = hq * 4 + wid;

  // A staging: thread -> (row ar, chunk apos); window rows are 8 chunks of 8 consecutive m
  const int ar = tid >> 2, apos = tid & 3;
  const int ag = ar >> 3, awl = ar & 7;
  const u16* gA = xb + ((size_t)nimg * 4096 + (a * 8 + ag) * 64 + b * 8 + awl) * 512
                  + (apos ^ ((ar >> 1) & 3)) * 8;

  // B staging: 384 rows ([hl][s][d] -> wqkvT row n = s*512+(hq*4+hl)*32+d), 6 chunks/thread
  const u16* gBp[6];
#pragma unroll
  for (int g = 0; g < 6; ++g) {
    const int brow = g * 64 + (tid >> 2);
    const int hl = brow / 96, rem = brow - hl * 96;
    const int n = (rem >> 5) * 512 + (hq * 4 + hl) * 32 + (rem & 31);
    gBp[g] = wqkvT + (size_t)n * 512 + ((tid & 3) ^ ((brow >> 1) & 3)) * 8;
  }

  auto STAGE = [&](int s) {
    const int k = s * 32;
    const int ba = (s & 1) * 2048, bb = (s & 1) * 12288;
    gload16(gA + k, &ldsA[ba + tid * 8]);
#pragma unroll
    for (int g = 0; g < 6; ++g)
      gload16(gBp[g] + k, &ldsB[bb + (g * 256 + tid) * 8]);
  };

  STAGE(0);
  f32x4 acc[4][6] = {};   // [m-frag][q0,q1,k0,k1,v0,v1]

  for (int kt = 0; kt < 16; ++kt) {
    const int ba = (kt & 1) * 2048, bb = (kt & 1) * 12288;
    if (kt < 15) { STAGE(kt + 1); WAITVM(7); }
    else         { WAITVM(0); }
    BARRIER();
    s16x8 af[4], bf[6];
#pragma unroll
    for (int mf = 0; mf < 4; ++mf) {
      const int row = mf * 16 + col_l;
      af[mf] = *(const s16x8*)&ldsA[ba + row * 32 + ((quad ^ ((row >> 1) & 3)) * 8)];
    }
#pragma unroll
    for (int nf = 0; nf < 6; ++nf) {
      const int brow = wid * 96 + (nf >> 1) * 32 + (nf & 1) * 16 + col_l;
      bf[nf] = *(const s16x8*)&ldsB[bb + brow * 32 + ((quad ^ ((brow >> 1) & 3)) * 8)];
    }
    __builtin_amdgcn_s_setprio(1);
#pragma unroll
    for (int mf = 0; mf < 4; ++mf)
#pragma unroll
      for (int nf = 0; nf < 6; ++nf)
        acc[mf][nf] = mfma16(af[mf], bf[nf], acc[mf][nf]);
    __builtin_amdgcn_s_setprio(0);
    BARRIER();
  }
  // K-loop done; B-dbuf region dead -> per-wave attn scratch overlays it.

  u16* sq = &lds[4096 + wid * 4096];  // Q [64][32] swizzled (4KB)
  u16* sk = sq + 2048;                // K [64][32] swizzled (4KB)
  u16* sp = sq;                       // P [64][64] swizzled (8KB, overlays Q+K)

  const float scale = 0.17677669529663687f;  // 1/sqrt(32)
  const float* mrow = mask + (size_t)(a * 8 + b) * 4096;

  const float qb0 = qkv_b[head * 32 + col_l],        qb1 = qkv_b[head * 32 + 16 + col_l];
  const float kb0 = qkv_b[512 + head * 32 + col_l],  kb1 = qkv_b[512 + head * 32 + 16 + col_l];
  const float vb0 = qkv_b[1024 + head * 32 + col_l], vb1 = qkv_b[1024 + head * 32 + 16 + col_l];

  // ---- write Q (scaled+bias), K (bias) to scratch: [e][d], chunk ^= (e>>1)&3
#pragma unroll
  for (int r = 0; r < 4; ++r)
#pragma unroll
    for (int half = 0; half < 2; ++half)
#pragma unroll
      for (int i = 0; i < 4; ++i) {
        const int e = r * 16 + quad * 4 + i;
        const int d = half * 16 + col_l;
        const int sw = (((d >> 3) ^ ((e >> 1) & 3)) << 3) + (d & 7);
        sq[e * 32 + sw] = f2bf((acc[r][half][i] + (half ? qb1 : qb0)) * scale);
        sk[e * 32 + sw] = f2bf(acc[r][2 + half][i] + (half ? kb1 : kb0));
      }

  // ---- S = Q K^T
  float rinv[4][4];
  {
    s16x8 aq[4], bk[4];
    const int ssw = (quad ^ ((col_l >> 1) & 3)) << 3;
#pragma unroll
    for (int t = 0; t < 4; ++t) {
      aq[t] = *(const s16x8*)&sq[(t * 16 + col_l) * 32 + ssw];
      bk[t] = *(const s16x8*)&sk[(t * 16 + col_l) * 32 + ssw];
    }
    f32x4 s[4][4] = {};
#pragma unroll
    for (int r = 0; r < 4; ++r)
#pragma unroll
      for (int c = 0; c < 4; ++c)
        s[r][c] = mfma16(aq[r], bk[c], s[r][c]);

    // bias + mask
#pragma unroll
    for (int r = 0; r < 4; ++r)
#pragma unroll
      for (int c = 0; c < 4; ++c)
#pragma unroll
        for (int i = 0; i < 4; ++i) {
          const int row = r * 16 + quad * 4 + i, col = c * 16 + col_l;
          const int dh = (row >> 3) - (col >> 3) + 7;
          const int dw = (row & 7) - (col & 7) + 7;
          s[r][c][i] += btab[(dh * 15 + dw) * 16 + head] + mrow[row * 64 + col];
        }

    // softmax (deferred 1/sum)
#pragma unroll
    for (int r = 0; r < 4; ++r) {
#pragma unroll
      for (int i = 0; i < 4; ++i) {
        float mx = fmaxf(fmaxf(s[r][0][i], s[r][1][i]), fmaxf(s[r][2][i], s[r][3][i]));
        mx = fmaxf(mx, __shfl_xor(mx, 1));
        mx = fmaxf(mx, __shfl_xor(mx, 2));
        mx = fmaxf(mx, __shfl_xor(mx, 4));
        mx = fmaxf(mx, __shfl_xor(mx, 8));
        float sum = 0.f;
#pragma unroll
        for (int c = 0; c < 4; ++c) {
          float p = __expf(s[r][c][i] - mx);
          s[r][c][i] = p;
          sum += p;
        }
        sum += __shfl_xor(sum, 1);
        sum += __shfl_xor(sum, 2);
        sum += __shfl_xor(sum, 4);
        sum += __shfl_xor(sum, 8);
        rinv[r][i] = 1.0f / sum;
      }
    }

    // P -> scratch (overlays Q+K; both consumed)
#pragma unroll
    for (int r = 0; r < 4; ++r)
#pragma unroll
      for (int c = 0; c < 4; ++c)
#pragma unroll
        for (int i = 0; i < 4; ++i) {
          const int row = r * 16 + quad * 4 + i, col = c * 16 + col_l;
          sp[(row * 64 + col) ^ ((row & 7) << 3)] = f2bf(s[r][c][i]);
        }
  }

  // ---- V: C-frag -> PV B-frag purely in registers (cross-quad shuffle)
  s16x8 bv[2][2];
#pragma unroll
  for (int cf = 0; cf < 2; ++cf) {
    const float vb = cf ? vb1 : vb0;
#pragma unroll
    for (int ks = 0; ks < 2; ++ks) {
      const int rA = ks * 2, rB = ks * 2 + 1;
      u32 A0 = pk2(acc[rA][4 + cf][0] + vb, acc[rA][4 + cf][1] + vb);
      u32 A1 = pk2(acc[rA][4 + cf][2] + vb, acc[rA][4 + cf][3] + vb);
      u32 B0 = pk2(acc[rB][4 + cf][0] + vb, acc[rB][4 + cf][1] + vb);
      u32 B1 = pk2(acc[rB][4 + cf][2] + vb, acc[rB][4 + cf][3] + vb);
      const int l0 = ((quad * 2) & 3) * 16 + col_l;
      const int l1 = ((quad * 2 + 1) & 3) * 16 + col_l;
      u32 a0 = (u32)__shfl((int)A0, l0), a1 = (u32)__shfl((int)A1, l0);
      u32 a2 = (u32)__shfl((int)A0, l1), a3 = (u32)__shfl((int)A1, l1);
      u32 b0 = (u32)__shfl((int)B0, l0), b1 = (u32)__shfl((int)B1, l0);
      u32 b2 = (u32)__shfl((int)B0, l1), b3 = (u32)__shfl((int)B1, l1);
      u32x4 wv;
      if (quad < 2) { wv[0] = a0; wv[1] = a1; wv[2] = a2; wv[3] = a3; }
      else          { wv[0] = b0; wv[1] = b1; wv[2] = b2; wv[3] = b3; }
      bv[cf][ks] = __builtin_bit_cast(s16x8, wv);
    }
  }

  // ---- O = P V
  f32x4 o[4][2] = {};
#pragma unroll
  for (int r = 0; r < 4; ++r) {
#pragma unroll
    for (int ks = 0; ks < 2; ++ks) {
      const int row = r * 16 + col_l;
      s16x8 pa = *(const s16x8*)&sp[(row * 64 + ks * 32 + quad * 8) ^ ((row & 7) << 3)];
#pragma unroll
      for (int cf = 0; cf < 2; ++cf)
        o[r][cf] = mfma16(pa, bv[cf][ks], o[r][cf]);
    }
  }

  // ---- normalize + 4x4 shuffle transpose -> 8B stores to AO [m][512]
#pragma unroll
  for (int r = 0; r < 4; ++r) {
#pragma unroll
    for (int cf = 0; cf < 2; ++cf) {
      float v0 = o[r][cf][0] * rinv[r][0], v1 = o[r][cf][1] * rinv[r][1];
      float v2 = o[r][cf][2] * rinv[r][2], v3 = o[r][cf][3] * rinv[r][3];
      float sA = (lane & 1) ? v0 : v1; sA = __shfl_xor(sA, 1);
      float sB = (lane & 1) ? v2 : v3; sB = __shfl_xor(sB, 1);
      u32 pa_, pb_;
      if (lane & 1) { pa_ = pk2(sA, v1); pb_ = pk2(sB, v3); }
      else          { pa_ = pk2(v0, sA); pb_ = pk2(v2, sB); }
      u32 s2 = (lane & 2) ? pa_ : pb_;
      s2 = (u32)__shfl_xor((int)s2, 2);
      u32x2 val;
      if (lane & 2) { val.x = s2;  val.y = pb_; }
      else          { val.x = pa_; val.y = s2;  }
      const int e = r * 16 + quad * 4 + (col_l & 3);
      const int h = a * 8 + (e >> 3), w = b * 8 + (e & 7);
      const size_t m = (size_t)nimg * 4096 + (size_t)h * 64 + w;
      *(u32x2*)&AO[m * 512 + head * 32 + cf * 16 + (col_l & ~3)] = val;
    }
  }
}

// ---------------- GEMM2: 128x128 tile, BK=32, 4 waves, dbuf, 4 blocks/CU (r12 MODE 1) ----------------
__global__ __launch_bounds__(256, 4)
void k_gemm2(const u16* __restrict__ A, const u16* __restrict__ B,
             const float* __restrict__ bias, float* __restrict__ Out, int ntn) {
  __shared__ u16 lds[16384];        // 32 KiB
  u16* ldsA = lds;                  // [2][4096]
  u16* ldsB = lds + 8192;           // [2][4096]
  const int tid = threadIdx.x;
  const int lane = tid & 63, wid = tid >> 6;
  const int quad = lane >> 4, col_l = lane & 15;
  const int wr = wid >> 1, wc = wid & 1;

  const int cpx = gridDim.x >> 3;
  const int sb = (blockIdx.x & 7) * cpx + (blockIdx.x >> 3);
  const int mt = sb / ntn, nt = sb - mt * ntn;
  const int m0 = mt * 128, n0 = nt * 128;

  const int sr = tid >> 2, sp_ = tid & 3;
  const size_t gA = (size_t)(m0 + sr) * 512 + (sp_ ^ ((sr >> 1) & 3)) * 8;
  const size_t gB = (size_t)(n0 + sr) * 512 + (sp_ ^ ((sr >> 1) & 3)) * 8;

  auto STAGE = [&](int s) {
    const int b = (s & 1) * 4096;
    const int k = s * 32;
    gload16(A + gA + k, &ldsA[b + tid * 8]);
    gload16(A + gA + 64 * 512 + k, &ldsA[b + 2048 + tid * 8]);
    gload16(B + gB + k, &ldsB[b + tid * 8]);
    gload16(B + gB + 64 * 512 + k, &ldsB[b + 2048 + tid * 8]);
  };

  STAGE(0);
  f32x4 acc[4][4] = {};

  for (int kt = 0; kt < 16; ++kt) {
    const int bu = (kt & 1) * 4096;
    if (kt < 15) { STAGE(kt + 1); WAITVM(4); }
    else         { WAITVM(0); }
    BARRIER();
    s16x8 af[4], bf[4];
#pragma unroll
    for (int mf = 0; mf < 4; ++mf) {
      const int row = wr * 64 + mf * 16 + col_l;
      af[mf] = *(const s16x8*)&ldsA[bu + row * 32 + ((quad ^ ((row >> 1) & 3)) * 8)];
    }
#pragma unroll
    for (int nf = 0; nf < 4; ++nf) {
      const int row = wc * 64 + nf * 16 + col_l;
      bf[nf] = *(const s16x8*)&ldsB[bu + row * 32 + ((quad ^ ((row >> 1) & 3)) * 8)];
    }
    __builtin_amdgcn_s_setprio(1);
#pragma unroll
    for (int mf = 0; mf < 4; ++mf)
#pragma unroll
      for (int nf = 0; nf < 4; ++nf)
        acc[mf][nf] = mfma16(af[mf], bf[nf], acc[mf][nf]);
    __builtin_amdgcn_s_setprio(0);
    BARRIER();
  }

  // fp32 epilogue: two 64-row passes through LDS (f32 [64][128] = 32 KB)
#pragma unroll
  for (int p = 0; p < 2; ++p) {
    if (p) __syncthreads();
    if (wr == p) {
#pragma unroll
      for (int c = 0; c < 4; ++c) {
        const float bv = bias[n0 + wc * 64 + c * 16 + col_l];
#pragma unroll
        for (int r = 0; r < 4; ++r) {
          float v0 = acc[r][c][0] + bv, v1 = acc[r][c][1] + bv;
          float v2 = acc[r][c][2] + bv, v3 = acc[r][c][3] + bv;
          float sA = (lane & 1) ? v0 : v1; sA = __shfl_xor(sA, 1);
          float sB = (lane & 1) ? v2 : v3; sB = __shfl_xor(sB, 1);
          float A0, A1, B0, B1;
          if (lane & 1) { A0 = sA; A1 = v1; B0 = sB; B1 = v3; }
          else          { A0 = v0; A1 = sA; B0 = v2; B1 = sB; }
          float t0 = (lane & 2) ? A0 : B0; t0 = __shfl_xor(t0, 2);
          float t1 = (lane & 2) ? A1 : B1; t1 = __shfl_xor(t1, 2);
          f32x4 outv;
          if (lane & 2) { outv[0] = t0; outv[1] = t1; outv[2] = B0; outv[3] = B1; }
          else          { outv[0] = A0; outv[1] = A1; outv[2] = t0; outv[3] = t1; }
          const int lr = r * 16 + quad * 4 + (col_l & 3);
          const int ck = (wc * 64 + c * 16 + (col_l & ~3)) >> 2;
          *(f32x4*)((char*)lds + lr * 512 + ((ck ^ (lr & 7)) << 4)) = outv;
        }
      }
    }
    __syncthreads();
#pragma unroll
    for (int it = 0; it < 8; ++it) {
      const int row = it * 8 + (tid >> 5);
      const int cl = tid & 31;
      f32x4 v = *(const f32x4*)((char*)lds + row * 512 + ((cl ^ (row & 7)) << 4));
      const int m = m0 + p * 64 + row;
      *(f32x4*)&Out[(size_t)m * 512 + n0 + cl * 4] = v;
    }
  }
}

// ---------------- launch ----------------
extern "C" void kernel_launch(void* const* d_in, const int* in_sizes, int n_in,
                              void* d_out, int out_size, void* d_ws, size_t ws_size,
                              hipStream_t stream) {
  const float* x     = (const float*)d_in[0];
  const float* mask  = (const float*)d_in[1];
  const float* qkv_w = (const float*)d_in[2];
  const float* qkv_b = (const float*)d_in[3];
  const float* out_w = (const float*)d_in[4];
  const float* out_b = (const float*)d_in[5];
  const float* btab  = (const float*)d_in[6];

  char* ws = (char*)d_ws;
  u16* xb    = (u16*)ws;                        // 134,217,728 B (x bf16)
  u16* ao    = (u16*)(ws + 134217728);          // 134,217,728 B (attn out bf16)
  u16* wqkvT = (u16*)(ws + 268435456);          // 1,572,864 B
  u16* woT   = (u16*)(ws + 270008320);          // 524,288 B

  k_conv_x<<<32768, 256, 0, stream>>>(x, xb, 8388608);
  k_transpose_w<<<3072, 256, 0, stream>>>(qkv_w, wqkvT, 512, 1536);
  k_transpose_w<<<1024, 256, 0, stream>>>(out_w, woT, 512, 512);
  k_winfuse<<<8192, 256, 0, stream>>>(xb, wqkvT, qkv_b, mask, btab, ao);
  k_gemm2<<<4096, 256, 0, stream>>>(ao, woT, out_b, (float*)d_out, 4);
}

// Round 14
// 586.252 us; speedup vs baseline: 1.2523x; 1.1768x over previous
//
#include <hip/hip_runtime.h>
#include <hip/hip_bf16.h>
#include <stdint.h>

// Swin windowed MHA: N=32, H=W=64, C=512, heads=16, head_dim=32, window 8x8 (E=64).
// conv x->bf16 ; pack qkv_w (fragment order) ; transpose out_w ;
// k_winfuse (fused QKV-proj + windowed attn: block = (window, head-quad), 4 waves,
// B direct from packed PW (L2), A via gload_lds dbuf, 40KB LDS, 3 blocks/CU) ;
// GEMM2 (r12 structure, fp32 out).

typedef __attribute__((ext_vector_type(4))) float  f32x4;
typedef __attribute__((ext_vector_type(4))) float  fvec4;
typedef __attribute__((ext_vector_type(8))) short  s16x8;
typedef __attribute__((ext_vector_type(8))) __bf16 bf16x8;
typedef __attribute__((ext_vector_type(2))) unsigned int u32x2;
typedef __attribute__((ext_vector_type(4))) unsigned int u32x4;
typedef unsigned short u16;
typedef unsigned int   u32;
typedef __attribute__((ext_vector_type(4))) u16 u16x4;
typedef __attribute__((ext_vector_type(8))) u16 u16x8;

__device__ __forceinline__ u16 f2bf(float f) {
  u32 u = __builtin_bit_cast(u32, f);
  u32 r = (u + 0x7FFFu + ((u >> 16) & 1u)) >> 16;
  return (u16)r;
}
__device__ __forceinline__ u32 pk2(float x, float y) {
  return (u32)f2bf(x) | ((u32)f2bf(y) << 16);
}

__device__ __forceinline__ f32x4 mfma16(s16x8 a, s16x8 b, f32x4 c) {
  return __builtin_amdgcn_mfma_f32_16x16x32_bf16((bf16x8)a, (bf16x8)b, c, 0, 0, 0);
}

__device__ __forceinline__ void gload16(const u16* g, u16* l) {
  __builtin_amdgcn_global_load_lds(
      (const __attribute__((address_space(1))) u32*)g,
      (__attribute__((address_space(3))) u32*)l, 16, 0, 0);
}

#define BARRIER() asm volatile("s_barrier" ::: "memory")
#define WAITVM(n) asm volatile("s_waitcnt vmcnt(" #n ")" ::: "memory")

// ---------------- conversion / packing kernels ----------------
__global__ void k_conv_x(const float* __restrict__ x, u16* __restrict__ xb, int n8) {
  int i = blockIdx.x * 256 + threadIdx.x;
  if (i >= n8) return;
  fvec4 v0 = ((const fvec4*)x)[i * 2];
  fvec4 v1 = ((const fvec4*)x)[i * 2 + 1];
  u16x8 o;
  o[0] = f2bf(v0.x); o[1] = f2bf(v0.y); o[2] = f2bf(v0.z); o[3] = f2bf(v0.w);
  o[4] = f2bf(v1.x); o[5] = f2bf(v1.y); o[6] = f2bf(v1.z); o[7] = f2bf(v1.w);
  ((u16x8*)xb)[i] = o;
}

__global__ void k_transpose_w(const float* __restrict__ w, u16* __restrict__ wt, int K, int N) {
  int i = blockIdx.x * 256 + threadIdx.x;
  if (i >= K * N) return;
  int k = i / N, n = i - k * N;
  wt[n * K + k] = f2bf(w[i]);
}

// pack qkv_w [512][1536] f32 -> PW bf16 fragment order (r6-validated):
// PW[(((H*3+s)*2+nf)*16+kt)*64+lane][8]; col = s*512+H*32+nf*16+(lane&15),
// k = kt*32+(lane>>4)*8 + 0..7
__global__ void k_pack_wqkv(const float* __restrict__ w, u16* __restrict__ pw) {
  int id = blockIdx.x * 256 + threadIdx.x;
  const int lane = id & 63;
  int r = id >> 6;
  const int kt = r & 15; r >>= 4;
  const int nf = r & 1;  r >>= 1;
  const int s = r % 3;
  const int H = r / 3;
  const int n = s * 512 + H * 32 + nf * 16 + (lane & 15);
  const int k0 = kt * 32 + (lane >> 4) * 8;
  u16 tmp[8];
#pragma unroll
  for (int j = 0; j < 8; ++j) tmp[j] = f2bf(w[(size_t)(k0 + j) * 1536 + n]);
  *(s16x8*)&pw[(size_t)id * 8] = *(const s16x8*)tmp;
}

// ---------------- fused QKV-proj + windowed attention ----------------
// Block = (window, head-quad): 8192 blocks, 256 thr = 4 waves, wave wid owns head hq*4+wid.
// Proj: M=64, per-wave N=96 ([Q32|K32|V32]), K=512, BK=32. A via gload_lds dbuf (8KB);
// B direct from packed PW (coalesced 1KB/fragment, L2-resident). LDS 40KB total
// (A dbuf 8KB + 4x8KB per-wave attn scratch) -> 3-4 blocks/CU.
__global__ __launch_bounds__(256, 3)
void k_winfuse(const u16* __restrict__ xb, const u16* __restrict__ PW,
               const float* __restrict__ qkv_b, const float* __restrict__ mask,
               const float* __restrict__ btab, u16* __restrict__ AO) {
  __shared__ u16 lds[20480];   // 40 KiB
  u16* ldsA = lds;             // [2][2048]
  const int tid = threadIdx.x;
  const int lane = tid & 63, wid = tid >> 6;
  const int quad = lane >> 4, col_l = lane & 15;

  // same-window blocks contiguous on one XCD
  const int sb = (blockIdx.x & 7) * 1024 + (blockIdx.x >> 3);
  const int win = sb >> 2, hq = sb & 3;
  const int nimg = win >> 6, a = (win >> 3) & 7, b = win & 7;
  const int head = hq * 4 + wid;

  // A staging: thread -> (row ar, chunk apos); window rows gathered from [nimg][h][w][512]
  const int ar = tid >> 2, apos = tid & 3;
  const int ag = ar >> 3, awl = ar & 7;
  const u16* gA = xb + ((size_t)nimg * 4096 + (a * 8 + ag) * 64 + b * 8 + awl) * 512
                  + (apos ^ ((ar >> 1) & 3)) * 8;

  auto STAGEA = [&](int s) {
    gload16(gA + s * 32, &ldsA[(s & 1) * 2048 + tid * 8]);
  };

  const u16* bpB = PW + (size_t)head * 6 * 8192;  // per-head fragment block

  STAGEA(0);
  f32x4 acc[4][6] = {};   // [m-frag][q0,q1,k0,k1,v0,v1]

#pragma unroll 1
  for (int kt = 0; kt < 16; ++kt) {
    const int ba = (kt & 1) * 2048;
    s16x8 bf[6];
#pragma unroll
    for (int nf = 0; nf < 6; ++nf)
      bf[nf] = *(const s16x8*)&bpB[(size_t)nf * 8192 + kt * 512 + lane * 8];
    if (kt < 15) { STAGEA(kt + 1); WAITVM(7); }   // drains A(kt); bf x6 + A(kt+1) in flight
    else         { WAITVM(6); }                   // drains A(15); bf x6 in flight
    BARRIER();
    s16x8 af[4];
#pragma unroll
    for (int mf = 0; mf < 4; ++mf) {
      const int row = mf * 16 + col_l;
      af[mf] = *(const s16x8*)&ldsA[ba + row * 32 + ((quad ^ ((row >> 1) & 3)) * 8)];
    }
    __builtin_amdgcn_s_setprio(1);
#pragma unroll
    for (int mf = 0; mf < 4; ++mf)
#pragma unroll
      for (int nf = 0; nf < 6; ++nf)
        acc[mf][nf] = mfma16(af[mf], bf[nf], acc[mf][nf]);
    __builtin_amdgcn_s_setprio(0);
    BARRIER();
  }

  // ---- attention tail (r13-validated, per-wave scratch) ----
  u16* sq = &lds[4096 + wid * 4096];  // Q [64][32] swizzled (4KB)
  u16* sk = sq + 2048;                // K [64][32] swizzled (4KB)
  u16* sp = sq;                       // P [64][64] swizzled (8KB, overlays Q+K)

  const float scale = 0.17677669529663687f;  // 1/sqrt(32)
  const float* mrow = mask + (size_t)(a * 8 + b) * 4096;

  const float qb0 = qkv_b[head * 32 + col_l],        qb1 = qkv_b[head * 32 + 16 + col_l];
  const float kb0 = qkv_b[512 + head * 32 + col_l],  kb1 = qkv_b[512 + head * 32 + 16 + col_l];
  const float vb0 = qkv_b[1024 + head * 32 + col_l], vb1 = qkv_b[1024 + head * 32 + 16 + col_l];

  // write Q (scaled+bias), K (bias) to scratch: [e][d], chunk ^= (e>>1)&3
#pragma unroll
  for (int r = 0; r < 4; ++r)
#pragma unroll
    for (int half = 0; half < 2; ++half)
#pragma unroll
      for (int i = 0; i < 4; ++i) {
        const int e = r * 16 + quad * 4 + i;
        const int d = half * 16 + col_l;
        const int sw = (((d >> 3) ^ ((e >> 1) & 3)) << 3) + (d & 7);
        sq[e * 32 + sw] = f2bf((acc[r][half][i] + (half ? qb1 : qb0)) * scale);
        sk[e * 32 + sw] = f2bf(acc[r][2 + half][i] + (half ? kb1 : kb0));
      }

  // S = Q K^T
  float rinv[4][4];
  {
    s16x8 aq[4], bk[4];
    const int ssw = (quad ^ ((col_l >> 1) & 3)) << 3;
#pragma unroll
    for (int t = 0; t < 4; ++t) {
      aq[t] = *(const s16x8*)&sq[(t * 16 + col_l) * 32 + ssw];
      bk[t] = *(const s16x8*)&sk[(t * 16 + col_l) * 32 + ssw];
    }
    f32x4 s[4][4] = {};
#pragma unroll
    for (int r = 0; r < 4; ++r)
#pragma unroll
      for (int c = 0; c < 4; ++c)
        s[r][c] = mfma16(aq[r], bk[c], s[r][c]);

    // bias + mask
#pragma unroll
    for (int r = 0; r < 4; ++r)
#pragma unroll
      for (int c = 0; c < 4; ++c)
#pragma unroll
        for (int i = 0; i < 4; ++i) {
          const int row = r * 16 + quad * 4 + i, col = c * 16 + col_l;
          const int dh = (row >> 3) - (col >> 3) + 7;
          const int dw = (row & 7) - (col & 7) + 7;
          s[r][c][i] += btab[(dh * 15 + dw) * 16 + head] + mrow[row * 64 + col];
        }

    // softmax (deferred 1/sum)
#pragma unroll
    for (int r = 0; r < 4; ++r) {
#pragma unroll
      for (int i = 0; i < 4; ++i) {
        float mx = fmaxf(fmaxf(s[r][0][i], s[r][1][i]), fmaxf(s[r][2][i], s[r][3][i]));
        mx = fmaxf(mx, __shfl_xor(mx, 1));
        mx = fmaxf(mx, __shfl_xor(mx, 2));
        mx = fmaxf(mx, __shfl_xor(mx, 4));
        mx = fmaxf(mx, __shfl_xor(mx, 8));
        float sum = 0.f;
#pragma unroll
        for (int c = 0; c < 4; ++c) {
          float p = __expf(s[r][c][i] - mx);
          s[r][c][i] = p;
          sum += p;
        }
        sum += __shfl_xor(sum, 1);
        sum += __shfl_xor(sum, 2);
        sum += __shfl_xor(sum, 4);
        sum += __shfl_xor(sum, 8);
        rinv[r][i] = 1.0f / sum;
      }
    }

    // P -> scratch (overlays Q+K; both consumed)
#pragma unroll
    for (int r = 0; r < 4; ++r)
#pragma unroll
      for (int c = 0; c < 4; ++c)
#pragma unroll
        for (int i = 0; i < 4; ++i) {
          const int row = r * 16 + quad * 4 + i, col = c * 16 + col_l;
          sp[(row * 64 + col) ^ ((row & 7) << 3)] = f2bf(s[r][c][i]);
        }
  }

  // V: C-frag -> PV B-frag purely in registers (cross-quad shuffle)
  s16x8 bv[2][2];
#pragma unroll
  for (int cf = 0; cf < 2; ++cf) {
    const float vb = cf ? vb1 : vb0;
#pragma unroll
    for (int ks = 0; ks < 2; ++ks) {
      const int rA = ks * 2, rB = ks * 2 + 1;
      u32 A0 = pk2(acc[rA][4 + cf][0] + vb, acc[rA][4 + cf][1] + vb);
      u32 A1 = pk2(acc[rA][4 + cf][2] + vb, acc[rA][4 + cf][3] + vb);
      u32 B0 = pk2(acc[rB][4 + cf][0] + vb, acc[rB][4 + cf][1] + vb);
      u32 B1 = pk2(acc[rB][4 + cf][2] + vb, acc[rB][4 + cf][3] + vb);
      const int l0 = ((quad * 2) & 3) * 16 + col_l;
      const int l1 = ((quad * 2 + 1) & 3) * 16 + col_l;
      u32 a0 = (u32)__shfl((int)A0, l0), a1 = (u32)__shfl((int)A1, l0);
      u32 a2 = (u32)__shfl((int)A0, l1), a3 = (u32)__shfl((int)A1, l1);
      u32 b0 = (u32)__shfl((int)B0, l0), b1 = (u32)__shfl((int)B1, l0);
      u32 b2 = (u32)__shfl((int)B0, l1), b3 = (u32)__shfl((int)B1, l1);
      u32x4 wv;
      if (quad < 2) { wv[0] = a0; wv[1] = a1; wv[2] = a2; wv[3] = a3; }
      else          { wv[0] = b0; wv[1] = b1; wv[2] = b2; wv[3] = b3; }
      bv[cf][ks] = __builtin_bit_cast(s16x8, wv);
    }
  }

  // O = P V
  f32x4 o[4][2] = {};
#pragma unroll
  for (int r = 0; r < 4; ++r) {
#pragma unroll
    for (int ks = 0; ks < 2; ++ks) {
      const int row = r * 16 + col_l;
      s16x8 pa = *(const s16x8*)&sp[(row * 64 + ks * 32 + quad * 8) ^ ((row & 7) << 3)];
#pragma unroll
      for (int cf = 0; cf < 2; ++cf)
        o[r][cf] = mfma16(pa, bv[cf][ks], o[r][cf]);
    }
  }

  // normalize + 4x4 shuffle transpose -> 8B stores to AO [m][512]
#pragma unroll
  for (int r = 0; r < 4; ++r) {
#pragma unroll
    for (int cf = 0; cf < 2; ++cf) {
      float v0 = o[r][cf][0] * rinv[r][0], v1 = o[r][cf][1] * rinv[r][1];
      float v2 = o[r][cf][2] * rinv[r][2], v3 = o[r][cf][3] * rinv[r][3];
      float sA = (lane & 1) ? v0 : v1; sA = __shfl_xor(sA, 1);
      float sB = (lane & 1) ? v2 : v3; sB = __shfl_xor(sB, 1);
      u32 pa_, pb_;
      if (lane & 1) { pa_ = pk2(sA, v1); pb_ = pk2(sB, v3); }
      else          { pa_ = pk2(v0, sA); pb_ = pk2(v2, sB); }
      u32 s2 = (lane & 2) ? pa_ : pb_;
      s2 = (u32)__shfl_xor((int)s2, 2);
      u32x2 val;
      if (lane & 2) { val.x = s2;  val.y = pb_; }
      else          { val.x = pa_; val.y = s2;  }
      const int e = r * 16 + quad * 4 + (col_l & 3);
      const int h = a * 8 + (e >> 3), w = b * 8 + (e & 7);
      const size_t m = (size_t)nimg * 4096 + (size_t)h * 64 + w;
      *(u32x2*)&AO[m * 512 + head * 32 + cf * 16 + (col_l & ~3)] = val;
    }
  }
}

// ---------------- GEMM2: 128x128 tile, BK=32, 4 waves, dbuf, 4 blocks/CU (r12) ----------------
__global__ __launch_bounds__(256, 4)
void k_gemm2(const u16* __restrict__ A, const u16* __restrict__ B,
             const float* __restrict__ bias, float* __restrict__ Out, int ntn) {
  __shared__ u16 lds[16384];        // 32 KiB
  u16* ldsA = lds;                  // [2][4096]
  u16* ldsB = lds + 8192;           // [2][4096]
  const int tid = threadIdx.x;
  const int lane = tid & 63, wid = tid >> 6;
  const int quad = lane >> 4, col_l = lane & 15;
  const int wr = wid >> 1, wc = wid & 1;

  const int cpx = gridDim.x >> 3;
  const int sb = (blockIdx.x & 7) * cpx + (blockIdx.x >> 3);
  const int mt = sb / ntn, nt = sb - mt * ntn;
  const int m0 = mt * 128, n0 = nt * 128;

  const int sr = tid >> 2, sp_ = tid & 3;
  const size_t gA = (size_t)(m0 + sr) * 512 + (sp_ ^ ((sr >> 1) & 3)) * 8;
  const size_t gB = (size_t)(n0 + sr) * 512 + (sp_ ^ ((sr >> 1) & 3)) * 8;

  auto STAGE = [&](int s) {
    const int b = (s & 1) * 4096;
    const int k = s * 32;
    gload16(A + gA + k, &ldsA[b + tid * 8]);
    gload16(A + gA + 64 * 512 + k, &ldsA[b + 2048 + tid * 8]);
    gload16(B + gB + k, &ldsB[b + tid * 8]);
    gload16(B + gB + 64 * 512 + k, &ldsB[b + 2048 + tid * 8]);
  };

  STAGE(0);
  f32x4 acc[4][4] = {};

  for (int kt = 0; kt < 16; ++kt) {
    const int bu = (kt & 1) * 4096;
    if (kt < 15) { STAGE(kt + 1); WAITVM(4); }
    else         { WAITVM(0); }
    BARRIER();
    s16x8 af[4], bf[4];
#pragma unroll
    for (int mf = 0; mf < 4; ++mf) {
      const int row = wr * 64 + mf * 16 + col_l;
      af[mf] = *(const s16x8*)&ldsA[bu + row * 32 + ((quad ^ ((row >> 1) & 3)) * 8)];
    }
#pragma unroll
    for (int nf = 0; nf < 4; ++nf) {
      const int row = wc * 64 + nf * 16 + col_l;
      bf[nf] = *(const s16x8*)&ldsB[bu + row * 32 + ((quad ^ ((row >> 1) & 3)) * 8)];
    }
    __builtin_amdgcn_s_setprio(1);
#pragma unroll
    for (int mf = 0; mf < 4; ++mf)
#pragma unroll
      for (int nf = 0; nf < 4; ++nf)
        acc[mf][nf] = mfma16(af[mf], bf[nf], acc[mf][nf]);
    __builtin_amdgcn_s_setprio(0);
    BARRIER();
  }

  // fp32 epilogue: two 64-row passes through LDS (f32 [64][128] = 32 KB)
#pragma unroll
  for (int p = 0; p < 2; ++p) {
    if (p) __syncthreads();
    if (wr == p) {
#pragma unroll
      for (int c = 0; c < 4; ++c) {
        const float bv = bias[n0 + wc * 64 + c * 16 + col_l];
#pragma unroll
        for (int r = 0; r < 4; ++r) {
          float v0 = acc[r][c][0] + bv, v1 = acc[r][c][1] + bv;
          float v2 = acc[r][c][2] + bv, v3 = acc[r][c][3] + bv;
          float sA = (lane & 1) ? v0 : v1; sA = __shfl_xor(sA, 1);
          float sB = (lane & 1) ? v2 : v3; sB = __shfl_xor(sB, 1);
          float A0, A1, B0, B1;
          if (lane & 1) { A0 = sA; A1 = v1; B0 = sB; B1 = v3; }
          else          { A0 = v0; A1 = sA; B0 = v2; B1 = sB; }
          float t0 = (lane & 2) ? A0 : B0; t0 = __shfl_xor(t0, 2);
          float t1 = (lane & 2) ? A1 : B1; t1 = __shfl_xor(t1, 2);
          f32x4 outv;
          if (lane & 2) { outv[0] = t0; outv[1] = t1; outv[2] = B0; outv[3] = B1; }
          else          { outv[0] = A0; outv[1] = A1; outv[2] = t0; outv[3] = t1; }
          const int lr = r * 16 + quad * 4 + (col_l & 3);
          const int ck = (wc * 64 + c * 16 + (col_l & ~3)) >> 2;
          *(f32x4*)((char*)lds + lr * 512 + ((ck ^ (lr & 7)) << 4)) = outv;
        }
      }
    }
    __syncthreads();
#pragma unroll
    for (int it = 0; it < 8; ++it) {
      const int row = it * 8 + (tid >> 5);
      const int cl = tid & 31;
      f32x4 v = *(const f32x4*)((char*)lds + row * 512 + ((cl ^ (row & 7)) << 4));
      const int m = m0 + p * 64 + row;
      *(f32x4*)&Out[(size_t)m * 512 + n0 + cl * 4] = v;
    }
  }
}

// ---------------- launch ----------------
extern "C" void kernel_launch(void* const* d_in, const int* in_sizes, int n_in,
                              void* d_out, int out_size, void* d_ws, size_t ws_size,
                              hipStream_t stream) {
  const float* x     = (const float*)d_in[0];
  const float* mask  = (const float*)d_in[1];
  const float* qkv_w = (const float*)d_in[2];
  const float* qkv_b = (const float*)d_in[3];
  const float* out_w = (const float*)d_in[4];
  const float* out_b = (const float*)d_in[5];
  const float* btab  = (const float*)d_in[6];

  char* ws = (char*)d_ws;
  u16* xb    = (u16*)ws;                        // 134,217,728 B (x bf16)
  u16* ao    = (u16*)(ws + 134217728);          // 134,217,728 B (attn out bf16)
  u16* pw    = (u16*)(ws + 268435456);          // 1,572,864 B (packed qkv_w)
  u16* woT   = (u16*)(ws + 270008320);          // 524,288 B

  k_conv_x<<<32768, 256, 0, stream>>>(x, xb, 8388608);
  k_pack_wqkv<<<384, 256, 0, stream>>>(qkv_w, pw);
  k_transpose_w<<<1024, 256, 0, stream>>>(out_w, woT, 512, 512);
  k_winfuse<<<8192, 256, 0, stream>>>(xb, pw, qkv_b, mask, btab, ao);
  k_gemm2<<<4096, 256, 0, stream>>>(ao, woT, out_b, (float*)d_out, 4);
}